// Round 5
// baseline (423.849 us; speedup 1.0000x reference)
//
#include <hip/hip_runtime.h>

// Problem constants (B=2, S=2048, D_IN=2048, H=16, G=4, HD=128)
#define S_LEN 2048
#define NROWS 4096      // B*S
#define DIN   2048
#define DQKV  5120      // 4096 (q|gate) + 512 K + 512 V
#define DQG   4096

typedef __bf16 bf16x8 __attribute__((ext_vector_type(8)));
typedef float  floatx4 __attribute__((ext_vector_type(4)));
typedef unsigned short u16;

#define QK_SCALE 0.08838834764831845f   // 128^-0.5, folded into Q

__device__ __forceinline__ u16 f2bf(float f) {
  unsigned int u = __float_as_uint(f);
  u += 0x7fffu + ((u >> 16) & 1u);   // RNE
  return (u16)(u >> 16);
}
__device__ __forceinline__ float bf2f(u16 v) {
  return __uint_as_float(((unsigned int)v) << 16);
}
// XOR-8 chunk swizzle within each 64-element column group, keyed by row&7.
__device__ __forceinline__ int swz(int col, int row) {
  return (col & ~63) | ((((col >> 3) & 7) ^ (row & 7)) << 3) | (col & 7);
}

__device__ __forceinline__ void gload_lds16(const void* g, void* l) {
  __builtin_amdgcn_global_load_lds(
      (__attribute__((address_space(1))) void*)(void*)(g),
      (__attribute__((address_space(3))) void*)(l), 16, 0, 0);
}

// ---------------- x fp32 -> bf16, swizzled (C = 2048) ----------------
__global__ __launch_bounds__(256) void cvt_x(const float* __restrict__ src,
                                             u16* __restrict__ dst) {
  const int i = blockIdx.x * 256 + threadIdx.x;   // one float4 per thread
  const int row = i >> 9, col = (i & 511) << 2;   // 512 float4 per row
  const float4 v = reinterpret_cast<const float4*>(src)[i];
  ushort4 o;
  o.x = f2bf(v.x); o.y = f2bf(v.y); o.z = f2bf(v.z); o.w = f2bf(v.w);
  *reinterpret_cast<ushort4*>(dst + (size_t)row * DIN + swz(col, row)) = o;
}

// ---------------- transpose + convert + swizzle: src[R][C] f32 -> dst[C][R] bf16 ----------------
__global__ __launch_bounds__(256) void tcvt(const float* __restrict__ src,
                                            u16* __restrict__ dst,
                                            int R, int C, int dld) {
  __shared__ float tile[32][33];
  const int c0 = blockIdx.x * 32, r0 = blockIdx.y * 32;
  const int t = threadIdx.x;
  {
    const int rl = t >> 3, cl4 = (t & 7) * 4;
    const float4 v = *reinterpret_cast<const float4*>(src + (size_t)(r0 + rl) * C + c0 + cl4);
    tile[rl][cl4 + 0] = v.x; tile[rl][cl4 + 1] = v.y;
    tile[rl][cl4 + 2] = v.z; tile[rl][cl4 + 3] = v.w;
  }
  __syncthreads();
  {
    const int cl = t >> 3, rl4 = (t & 7) * 4;
    ushort4 o;
    o.x = f2bf(tile[rl4 + 0][cl]); o.y = f2bf(tile[rl4 + 1][cl]);
    o.z = f2bf(tile[rl4 + 2][cl]); o.w = f2bf(tile[rl4 + 3][cl]);
    const int rd = c0 + cl, cd = r0 + rl4;      // dst (row, col)
    *reinterpret_cast<ushort4*>(dst + (size_t)rd * dld + swz(cd, rd)) = o;
  }
}

// ---------------- bf16 GEMM, 128x128 tile, BK=64 (K|V proj + Wo GEMM) ----------------
// C[M][N] = A[M][K] @ Bt[N][K]^T ; A, Bt swz()-swizzled; C plain, leading dim ldc.
template <bool BF16_OUT>
__global__ __launch_bounds__(256) void gemm_bt(const u16* __restrict__ A,
                                               const u16* __restrict__ Bt,
                                               void* __restrict__ Cv,
                                               int M, int N, int K, int ldc) {
  __shared__ __align__(16) u16 As[128 * 64];
  __shared__ __align__(16) u16 Bs[128 * 64];
  const int tid = threadIdx.x, wv = tid >> 6, lane = tid & 63;
  const int m0 = blockIdx.y * 128, n0 = blockIdx.x * 128;
  const int wm = (wv >> 1) * 64, wn = (wv & 1) * 64;
  const int frow = lane & 15, quad = lane >> 4, fsw = frow & 7;
  const int srow = lane >> 3, scol = (lane & 7) * 8;
  floatx4 acc[4][4] = {};
  for (int k0 = 0; k0 < K; k0 += 64) {
#pragma unroll
    for (int i = 0; i < 4; ++i) {
      const int rr = (wv * 4 + i) * 8;
      gload_lds16(A  + (size_t)(m0 + rr + srow) * K + k0 + scol, &As[rr * 64]);
      gload_lds16(Bt + (size_t)(n0 + rr + srow) * K + k0 + scol, &Bs[rr * 64]);
    }
    __syncthreads();
#pragma unroll
    for (int ks = 0; ks < 2; ++ks) {
      bf16x8 af[4], bfr[4];
#pragma unroll
      for (int mi = 0; mi < 4; ++mi)
        af[mi] = *reinterpret_cast<const bf16x8*>(
            &As[(wm + mi * 16 + frow) * 64 + (((ks * 4 + quad) ^ fsw) << 3)]);
#pragma unroll
      for (int ni = 0; ni < 4; ++ni)
        bfr[ni] = *reinterpret_cast<const bf16x8*>(
            &Bs[(wn + ni * 16 + frow) * 64 + (((ks * 4 + quad) ^ fsw) << 3)]);
#pragma unroll
      for (int mi = 0; mi < 4; ++mi)
#pragma unroll
        for (int ni = 0; ni < 4; ++ni)
          acc[mi][ni] = __builtin_amdgcn_mfma_f32_16x16x32_bf16(af[mi], bfr[ni], acc[mi][ni], 0, 0, 0);
    }
    __syncthreads();
  }
  const int crow = (lane >> 4) * 4, ccol = lane & 15;
#pragma unroll
  for (int mi = 0; mi < 4; ++mi)
#pragma unroll
    for (int ni = 0; ni < 4; ++ni) {
      const size_t base = (size_t)(m0 + wm + mi * 16 + crow) * ldc + (n0 + wn + ni * 16 + ccol);
      if constexpr (BF16_OUT) {
        u16* C = (u16*)Cv;
#pragma unroll
        for (int r = 0; r < 4; ++r) C[base + (size_t)r * ldc] = f2bf(acc[mi][ni][r]);
      } else {
        float* C = (float*)Cv;
#pragma unroll
        for (int r = 0; r < 4; ++r) C[base + (size_t)r * ldc] = acc[mi][ni][r];
      }
    }
}

// ---------------- 8-phase deep-pipelined bf16 GEMM, 256x256 tile, BK=64 ----------------
// m201-verified geometry: 512 threads = 8 waves (2M x 4N), wave tile 128x64 ->
// acc[8][4] = 128 VGPRs (fits the 256-reg budget; round-1's 160 spilled).
// 16 MFMA per phase. LDS: 2 slots x (A 256x64 + B 256x64) = 128 KiB -> 1 WG/CU.
// Stage unit = 64 rows x 64 k = 8 KiB = 1 global_load_lds_dwordx4/thread;
// 8 units/tile (A0..A3, B0..B3). Deadness: (F0,ks) phases ds_read A0,A2;
// (F1,ks) read A1,A3; all B rows last read ph3 (slot0) / ph7 (slot1).
// Staging 3+3+2 per tile; each region dead one barrier before its stage.
// Counted vmcnt(3) at ph4/ph8 only. sched_barrier(0) after each lgkmcnt(0)
// per guide rule #18 (prevents compiler hoisting MFMA past the wait).
__global__ __launch_bounds__(512, 2) void gemm256(const u16* __restrict__ A,
                                                  const u16* __restrict__ Bt,
                                                  u16* __restrict__ C,
                                                  int K, int ldc) {
  __shared__ __align__(16) u16 As[2][256 * 64];   // 64 KiB
  __shared__ __align__(16) u16 Bs[2][256 * 64];   // 64 KiB
  const int tid = threadIdx.x, wv = tid >> 6, lane = tid & 63;
  // XCD-bijective swizzle (grid = 256 WGs, multiple of 8)
  const int nx = gridDim.x;
  const int orig = blockIdx.y * nx + blockIdx.x;
  const int cpx = (nx * gridDim.y) >> 3;
  const int wgid = (orig & 7) * cpx + (orig >> 3);
  const int m0 = (wgid / nx) * 256, n0 = (wgid % nx) * 256;
  const int wm = (wv >> 2) * 128, wn = (wv & 3) * 64;
  const int f = lane & 15, quad = lane >> 4, fs = f & 7;

  const u16* Ab = A  + (size_t)(m0 + wv * 8 + (lane >> 3)) * K + (lane & 7) * 8;
  const u16* Bb = Bt + (size_t)(n0 + wv * 8 + (lane >> 3)) * K + (lane & 7) * 8;

  floatx4 acc[8][4] = {};
  bf16x8 af[4], bfr[4];

  auto stageA = [&](int sl, int t, int u) {
    gload_lds16(Ab + (size_t)u * 64 * K + (size_t)t * 64, &As[sl][(u * 64 + wv * 8) * 64]);
  };
  auto stageB = [&](int sl, int t, int u) {
    gload_lds16(Bb + (size_t)u * 64 * K + (size_t)t * 64, &Bs[sl][(u * 64 + wv * 8) * 64]);
  };
  auto loadA = [&](int sl, int fh, int ks) {
#pragma unroll
    for (int mf = 0; mf < 4; ++mf)
      af[mf] = *reinterpret_cast<const bf16x8*>(
          &As[sl][(wm + fh * 64 + mf * 16 + f) * 64 + ((((ks << 2) + quad) ^ fs) << 3)]);
  };
  auto loadB = [&](int sl, int ks) {
#pragma unroll
    for (int nf = 0; nf < 4; ++nf)
      bfr[nf] = *reinterpret_cast<const bf16x8*>(
          &Bs[sl][(wn + nf * 16 + f) * 64 + ((((ks << 2) + quad) ^ fs) << 3)]);
  };
  auto mmas = [&](int fh) {
#pragma unroll
    for (int mf = 0; mf < 4; ++mf)
#pragma unroll
      for (int nf = 0; nf < 4; ++nf)
        acc[fh * 4 + mf][nf] = __builtin_amdgcn_mfma_f32_16x16x32_bf16(
            af[mf], bfr[nf], acc[fh * 4 + mf][nf], 0, 0, 0);
  };
  auto wait_lds = [&]() {
    asm volatile("s_waitcnt lgkmcnt(0)" ::: "memory");
    __builtin_amdgcn_sched_barrier(0);   // rule #18: pin MFMA after the wait
  };

  // prologue: tile0 -> slot0 (8 units), then tile1 {A0,A2,B0} -> slot1 (in flight)
#pragma unroll
  for (int u = 0; u < 4; ++u) stageA(0, 0, u);
#pragma unroll
  for (int u = 0; u < 4; ++u) stageB(0, 0, u);
  stageA(1, 1, 0); stageA(1, 1, 2); stageB(1, 1, 0);
  asm volatile("s_waitcnt vmcnt(3)" ::: "memory");
  __builtin_amdgcn_s_barrier();

  const int IT = K >> 7;   // 2 K-tiles (BK=64 each) per iteration
#pragma unroll 1
  for (int i = 0; i < IT; ++i) {
    const int t0 = 2 * i;
    const bool st = (i < IT - 1);
    // ph1: slot0 (F0,k0); stage slot1(t0+1): A1,A3 (dead since end-ph8 prev), B1
    loadA(0, 0, 0); loadB(0, 0);
    stageA(1, t0 + 1, 1); stageA(1, t0 + 1, 3); stageB(1, t0 + 1, 1);
    __builtin_amdgcn_s_barrier();
    wait_lds();
    __builtin_amdgcn_s_setprio(1); mmas(0); __builtin_amdgcn_s_setprio(0);
    __builtin_amdgcn_s_barrier();
    // ph2: slot0 (F1,k0); B(k0) frags reg-reused; stage slot1: B2,B3
    loadA(0, 1, 0);
    stageB(1, t0 + 1, 2); stageB(1, t0 + 1, 3);
    __builtin_amdgcn_s_barrier();
    wait_lds();
    __builtin_amdgcn_s_setprio(1); mmas(1); __builtin_amdgcn_s_setprio(0);
    __builtin_amdgcn_s_barrier();
    // ph3: slot0 (F0,k1)  [last ds_reads of slot0 A0,A2 + all B]
    loadA(0, 0, 1); loadB(0, 1);
    __builtin_amdgcn_s_barrier();
    wait_lds();
    __builtin_amdgcn_s_setprio(1); mmas(0); __builtin_amdgcn_s_setprio(0);
    __builtin_amdgcn_s_barrier();
    // ph4: slot0 (F1,k1); stage slot0'(t0+2): A0,A2,B0 (dead since end-ph3)
    // checkpoint: slot1(t0+1) fully landed (its last stage was ph2, 2 phases old)
    loadA(0, 1, 1);
    if (st) { stageA(0, t0 + 2, 0); stageA(0, t0 + 2, 2); stageB(0, t0 + 2, 0); }
    __builtin_amdgcn_s_barrier();
    wait_lds();
    __builtin_amdgcn_s_setprio(1); mmas(1); __builtin_amdgcn_s_setprio(0);
    if (st) { asm volatile("s_waitcnt vmcnt(3)" ::: "memory"); }
    else    { asm volatile("s_waitcnt vmcnt(0)" ::: "memory"); }
    __builtin_amdgcn_s_barrier();
    // ph5: slot1 (F0,k0); stage slot0': A1,A3 (dead since end-ph4), B1
    loadA(1, 0, 0); loadB(1, 0);
    if (st) { stageA(0, t0 + 2, 1); stageA(0, t0 + 2, 3); stageB(0, t0 + 2, 1); }
    __builtin_amdgcn_s_barrier();
    wait_lds();
    __builtin_amdgcn_s_setprio(1); mmas(0); __builtin_amdgcn_s_setprio(0);
    __builtin_amdgcn_s_barrier();
    // ph6: slot1 (F1,k0); stage slot0': B2,B3
    loadA(1, 1, 0);
    if (st) { stageB(0, t0 + 2, 2); stageB(0, t0 + 2, 3); }
    __builtin_amdgcn_s_barrier();
    wait_lds();
    __builtin_amdgcn_s_setprio(1); mmas(1); __builtin_amdgcn_s_setprio(0);
    __builtin_amdgcn_s_barrier();
    // ph7: slot1 (F0,k1)  [last ds_reads of slot1 A0,A2 + all B]
    loadA(1, 0, 1); loadB(1, 1);
    __builtin_amdgcn_s_barrier();
    wait_lds();
    __builtin_amdgcn_s_setprio(1); mmas(0); __builtin_amdgcn_s_setprio(0);
    __builtin_amdgcn_s_barrier();
    // ph8: slot1 (F1,k1); stage slot1''(t0+3): A0,A2,B0 (dead since end-ph7)
    // checkpoint: slot0'(t0+2) fully landed (its last stage was ph6, 2 phases old)
    loadA(1, 1, 1);
    if (st) { stageA(1, t0 + 3, 0); stageA(1, t0 + 3, 2); stageB(1, t0 + 3, 0); }
    __builtin_amdgcn_s_barrier();
    wait_lds();
    __builtin_amdgcn_s_setprio(1); mmas(1); __builtin_amdgcn_s_setprio(0);
    if (st) { asm volatile("s_waitcnt vmcnt(3)" ::: "memory"); }
    __builtin_amdgcn_s_barrier();
  }

  // epilogue: plain bf16 C write (C/D layout: col = lane&15, row = quad*4 + r)
#pragma unroll
  for (int mf = 0; mf < 8; ++mf)
#pragma unroll
    for (int nf = 0; nf < 4; ++nf) {
      const size_t base = (size_t)(m0 + wm + (mf >> 2) * 64 + (mf & 3) * 16 + quad * 4) * ldc
                        + (n0 + wn + nf * 16 + f);
#pragma unroll
      for (int r = 0; r < 4; ++r) C[base + (size_t)r * ldc] = f2bf(acc[mf][nf][r]);
    }
}

// ---------------- fused RMSNorm + RoPE for Q (scale folded in), bf16 in ----------------
__global__ __launch_bounds__(256) void qnorm_rope(const u16* __restrict__ QKV,
                                                  const float* __restrict__ w,
                                                  const float* __restrict__ cosT,
                                                  const float* __restrict__ sinT,
                                                  u16* __restrict__ Qb) {
  const int wv = threadIdx.x >> 6, lane = threadIdx.x & 63;
  const int idx = blockIdx.x * 4 + wv;      // row*16 + h
  const int h = idx & 15, row = idx >> 4;   // row = b*S + s
  const int s = row & (S_LEN - 1), b = row >> 11;
  const u16* base = QKV + (size_t)row * DQKV + h * 256;
  const float v0 = bf2f(base[lane]), v1 = bf2f(base[lane + 64]);
  float ss = v0 * v0 + v1 * v1;
#pragma unroll
  for (int m = 32; m >= 1; m >>= 1) ss += __shfl_xor(ss, m);
  const float rn = rsqrtf(ss * (1.0f / 128.0f) + 1e-6f) * QK_SCALE;
  const float n0 = v0 * rn * (1.0f + w[lane]);
  const float n1 = v1 * rn * (1.0f + w[lane + 64]);
  const float c0 = cosT[(size_t)s * 128 + lane], c1 = cosT[(size_t)s * 128 + lane + 64];
  const float sn0 = sinT[(size_t)s * 128 + lane], sn1 = sinT[(size_t)s * 128 + lane + 64];
  u16* qb = Qb + ((size_t)(b * 16 + h) * S_LEN + s) * 128;
  qb[lane]      = f2bf(n0 * c0 - n1 * sn0);
  qb[lane + 64] = f2bf(n1 * c1 + n0 * sn1);
}

// ---------------- fused RMSNorm + RoPE for K, XOR-swizzled attn layout ----------------
__global__ __launch_bounds__(256) void knorm_rope(const u16* __restrict__ QKV,
                                                  const float* __restrict__ w,
                                                  const float* __restrict__ cosT,
                                                  const float* __restrict__ sinT,
                                                  u16* __restrict__ Kb) {
  const int wv = threadIdx.x >> 6, lane = threadIdx.x & 63;
  const int idx = blockIdx.x * 4 + wv;      // row*4 + g
  const int g = idx & 3, row = idx >> 2;
  const int s = row & (S_LEN - 1), b = row >> 11;
  const u16* base = QKV + (size_t)row * DQKV + DQG + g * 128;
  const float v0 = bf2f(base[lane]), v1 = bf2f(base[lane + 64]);
  float ss = v0 * v0 + v1 * v1;
#pragma unroll
  for (int m = 32; m >= 1; m >>= 1) ss += __shfl_xor(ss, m);
  const float rn = rsqrtf(ss * (1.0f / 128.0f) + 1e-6f);
  const float n0 = v0 * rn * (1.0f + w[lane]);
  const float n1 = v1 * rn * (1.0f + w[lane + 64]);
  const float c0 = cosT[(size_t)s * 128 + lane], c1 = cosT[(size_t)s * 128 + lane + 64];
  const float sn0 = sinT[(size_t)s * 128 + lane], sn1 = sinT[(size_t)s * 128 + lane + 64];
  u16* kb = Kb + ((size_t)(b * 4 + g) * S_LEN + s) * 128;
  const int sw = s & 7;
  const int d0 = lane, d1 = lane + 64;
  const int p0 = (((d0 >> 3) ^ sw) << 3) | (d0 & 7);
  const int p1 = (((d1 >> 3) ^ sw) << 3) | (d1 & 7);
  kb[p0] = f2bf(n0 * c0 - n1 * sn0);
  kb[p1] = f2bf(n1 * c1 + n0 * sn1);
}

// ---------------- V: QKV bf16 cols 4608.. -> Vt bf16 [bg][d][s], attn-swizzled ----------------
__global__ __launch_bounds__(256) void vtrans(const u16* __restrict__ QKV,
                                              u16* __restrict__ Vt) {
  __shared__ u16 tile[32][40];
  const int bg = blockIdx.z;                 // b*4+g
  const int s0 = blockIdx.x * 32, d0 = blockIdx.y * 32;
  const int b = bg >> 2, g = bg & 3;
  const int t = threadIdx.x;
  {
    const int sl = t >> 3, dl4 = (t & 7) * 4;
    const ushort4 v = *reinterpret_cast<const ushort4*>(
        QKV + (size_t)(b * S_LEN + s0 + sl) * DQKV + DQG + 512 + g * 128 + d0 + dl4);
    tile[sl][dl4 + 0] = v.x; tile[sl][dl4 + 1] = v.y;
    tile[sl][dl4 + 2] = v.z; tile[sl][dl4 + 3] = v.w;
  }
  __syncthreads();
  {
    const int dl = t >> 3, sl4 = (t & 7) * 4;
    ushort4 o;
    o.x = tile[sl4 + 0][dl]; o.y = tile[sl4 + 1][dl];
    o.z = tile[sl4 + 2][dl]; o.w = tile[sl4 + 3][dl];
    const int d = d0 + dl, s = s0 + sl4;
    const size_t base = (size_t)(bg * 128 + d) * S_LEN + (s & ~63);
    const int pos = ((((s >> 3) & 7) ^ (d & 7)) << 3) | (s & 7);
    *reinterpret_cast<ushort4*>(Vt + base + pos) = o;
  }
}

// ---------------- MFMA flash attention + gating (no-max softmax, paired causal) ----------------
__global__ __launch_bounds__(256) void attn(const u16* __restrict__ Qb,
                                            const u16* __restrict__ Kb,
                                            const u16* __restrict__ Vt,
                                            const u16* __restrict__ QKV,
                                            u16* __restrict__ ctxg) {
  __shared__ __align__(16) u16 Ks[64 * 128];   // [key][d], chunk-swizzled
  __shared__ __align__(16) u16 Vts[128 * 64];  // [d][key], chunk-swizzled
  __shared__ __align__(16) u16 Ps[4][16 * 68]; // per-wave P [q][key], stride 68
  const int tid = threadIdx.x, wv = tid >> 6, lane = tid & 63;
  const int ip = blockIdx.x, bh = blockIdx.y;
  const int b = bh >> 4, h = bh & 15, g = h >> 2, bg = b * 4 + g;
  const int f = lane & 15, quad = lane >> 4, fq = quad * 8;
  const int fsw = f & 7;
  const u16* Kp = Kb + (size_t)bg * S_LEN * 128;
  const u16* Vp = Vt + (size_t)bg * 128 * S_LEN;
  u16* Pw = Ps[wv];

  for (int pass = 0; pass < 2; ++pass) {
    const int qt = pass ? 31 - ip : ip;
    const u16* Qp = Qb + ((size_t)bh * S_LEN + qt * 64 + wv * 16) * 128;
    bf16x8 aq[4];
#pragma unroll
    for (int c = 0; c < 4; ++c)
      aq[c] = *reinterpret_cast<const bf16x8*>(&Qp[(size_t)f * 128 + c * 32 + fq]);

    floatx4 o[8] = {};
    float lsum[4] = {0.f, 0.f, 0.f, 0.f};
    const int nkt = qt + 1;

    for (int kt = 0; kt < nkt; ++kt) {
      const int k0 = kt * 64;
#pragma unroll
      for (int i = 0; i < 4; ++i) {
        const int j = wv * 4 + i;
        gload_lds16(Kp + (size_t)k0 * 128 + j * 512 + lane * 8, &Ks[j * 512]);
      }
#pragma unroll
      for (int i = 0; i < 4; ++i) {
        const int r0 = (wv * 4 + i) * 8;
        gload_lds16(Vp + (size_t)(r0 + (lane >> 3)) * S_LEN + k0 + (lane & 7) * 8,
                    &Vts[r0 * 64]);
      }
      __syncthreads();

      floatx4 sc[4] = {};
#pragma unroll
      for (int c = 0; c < 4; ++c) {
#pragma unroll
        for (int n = 0; n < 4; ++n) {
          bf16x8 bk = *reinterpret_cast<const bf16x8*>(
              &Ks[(n * 16 + f) * 128 + (((4 * c + quad) ^ fsw) << 3)]);
          sc[n] = __builtin_amdgcn_mfma_f32_16x16x32_bf16(aq[c], bk, sc[n], 0, 0, 0);
        }
      }

      const int qrow0 = qt * 64 + wv * 16 + quad * 4;
#pragma unroll
      for (int n = 0; n < 4; ++n) {
        const int key = k0 + n * 16 + f;
#pragma unroll
        for (int r = 0; r < 4; ++r) {
          const float p = (key <= qrow0 + r) ? __expf(sc[n][r]) : 0.f;
          lsum[r] += p;
          Pw[(quad * 4 + r) * 68 + n * 16 + f] = f2bf(p);
        }
      }

#pragma unroll
      for (int kf = 0; kf < 2; ++kf) {
        bf16x8 pf = *reinterpret_cast<const bf16x8*>(&Pw[f * 68 + kf * 32 + fq]);
#pragma unroll
        for (int dt = 0; dt < 8; ++dt) {
          bf16x8 bv = *reinterpret_cast<const bf16x8*>(
              &Vts[(dt * 16 + f) * 64 + (((4 * kf + quad) ^ fsw) << 3)]);
          o[dt] = __builtin_amdgcn_mfma_f32_16x16x32_bf16(pf, bv, o[dt], 0, 0, 0);
        }
      }
      __syncthreads();
    }

#pragma unroll
    for (int r = 0; r < 4; ++r) {
#pragma unroll
      for (int mm = 8; mm >= 1; mm >>= 1) lsum[r] += __shfl_xor(lsum[r], mm);
    }

    // epilogue: 1/l, sigmoid gate (bf16), swizzled bf16 ctx write
#pragma unroll
    for (int r = 0; r < 4; ++r) {
      const int s = qt * 64 + wv * 16 + quad * 4 + r;
      const size_t grow = (size_t)b * S_LEN + s;
      const float inv = 1.0f / lsum[r];
#pragma unroll
      for (int dt = 0; dt < 8; ++dt) {
        const int d = dt * 16 + f;
        const float gate = bf2f(QKV[grow * DQKV + h * 256 + 128 + d]);
        const float val = o[dt][r] * inv * (1.0f / (1.0f + __expf(-gate)));
        const int col = h * 128 + d;
        ctxg[grow * 2048 + swz(col, (int)grow)] = f2bf(val);
      }
    }
  }
}

extern "C" void kernel_launch(void* const* d_in, const int* in_sizes, int n_in,
                              void* d_out, int out_size, void* d_ws, size_t ws_size,
                              hipStream_t stream) {
  const float* x    = (const float*)d_in[0];
  const float* Wq   = (const float*)d_in[1];
  const float* Wk   = (const float*)d_in[2];
  const float* Wv   = (const float*)d_in[3];
  const float* Wo   = (const float*)d_in[4];
  const float* qnw  = (const float*)d_in[5];
  const float* knw  = (const float*)d_in[6];
  const float* cosT = (const float*)d_in[7];
  const float* sinT = (const float*)d_in[8];
  // d_in[9] = mask (unused; causality computed analytically)

  char* p = (char*)d_ws;
  u16*   xb    = (u16*)p;  p += (size_t)NROWS * DIN * 2;       // x bf16 (swizzled)
  u16*   WqkvT = (u16*)p;  p += (size_t)DQKV * DIN * 2;        // [Wq|Wk|Wv]^T (swizzled)
  u16*   WoT   = (u16*)p;  p += (size_t)2048 * 2048 * 2;       // Wo^T (swizzled)
  u16*   QKVb  = (u16*)p;  p += (size_t)NROWS * DQKV * 2;      // qkv proj bf16 (plain)
  u16*   Qbf   = (u16*)p;  p += (size_t)2 * 16 * S_LEN * 128 * 2;
  u16*   Kbf   = (u16*)p;  p += (size_t)2 * 4 * S_LEN * 128 * 2;
  u16*   Vtb   = (u16*)p;  p += (size_t)2 * 4 * S_LEN * 128 * 2;
  u16*   ctxg  = (u16*)p;  p += (size_t)NROWS * 2048 * 2;      // gated ctx (swizzled)

  cvt_x<<<8192, 256, 0, stream>>>(x, xb);
  tcvt<<<dim3(128, 64), 256, 0, stream>>>(Wq, WqkvT, 2048, 4096, 2048);
  tcvt<<<dim3(16, 64), 256, 0, stream>>>(Wk, WqkvT + (size_t)4096 * 2048, 2048, 512, 2048);
  tcvt<<<dim3(16, 64), 256, 0, stream>>>(Wv, WqkvT + (size_t)4608 * 2048, 2048, 512, 2048);
  tcvt<<<dim3(64, 64), 256, 0, stream>>>(Wo, WoT, 2048, 2048, 2048);

  // Q|gate projection: 8-phase 256x256 pipeline, grid 16x16 = 256 WGs (1/CU, no tail)
  gemm256<<<dim3(16, 16), 512, 0, stream>>>(xb, WqkvT, QKVb, DIN, DQKV);
  // K|V projection: 128^2 tile, grid 8x32 = 256 WGs (1/CU, no tail)
  gemm_bt<true><<<dim3(8, 32), 256, 0, stream>>>(
      xb, WqkvT + (size_t)4096 * 2048, QKVb + 4096, NROWS, 1024, DIN, DQKV);

  qnorm_rope<<<16384, 256, 0, stream>>>(QKVb, qnw, cosT, sinT, Qbf);
  knorm_rope<<<4096, 256, 0, stream>>>(QKVb, knw, cosT, sinT, Kbf);
  vtrans<<<dim3(64, 4, 8), 256, 0, stream>>>(QKVb, Vtb);

  attn<<<dim3(16, 32), 256, 0, stream>>>(Qbf, Kbf, Vtb, QKVb, ctxg);

  gemm_bt<false><<<dim3(16, 32), 256, 0, stream>>>(ctxg, WoT, (float*)d_out, NROWS, 2048, 2048, 2048);
}

// Round 6
// 412.926 us; speedup vs baseline: 1.0265x; 1.0265x over previous
//
#include <hip/hip_runtime.h>

// Problem constants (B=2, S=2048, D_IN=2048, H=16, G=4, HD=128)
#define S_LEN 2048
#define NROWS 4096      // B*S
#define DIN   2048
#define DQKV  5120      // 4096 (q|gate) + 512 K + 512 V
#define DQG   4096

typedef __bf16 bf16x8 __attribute__((ext_vector_type(8)));
typedef float  floatx4 __attribute__((ext_vector_type(4)));
typedef unsigned short u16;

#define QK_SCALE 0.08838834764831845f   // 128^-0.5, folded into Q

__device__ __forceinline__ u16 f2bf(float f) {
  unsigned int u = __float_as_uint(f);
  u += 0x7fffu + ((u >> 16) & 1u);   // RNE
  return (u16)(u >> 16);
}
__device__ __forceinline__ float bf2f(u16 v) {
  return __uint_as_float(((unsigned int)v) << 16);
}
// XOR-8 chunk swizzle within each 64-element column group, keyed by row&7.
__device__ __forceinline__ int swz(int col, int row) {
  return (col & ~63) | ((((col >> 3) & 7) ^ (row & 7)) << 3) | (col & 7);
}

__device__ __forceinline__ void gload_lds16(const void* g, void* l) {
  __builtin_amdgcn_global_load_lds(
      (__attribute__((address_space(1))) void*)(void*)(g),
      (__attribute__((address_space(3))) void*)(l), 16, 0, 0);
}

// ---------------- x fp32 -> bf16, swizzled (C = 2048) ----------------
__global__ __launch_bounds__(256) void cvt_x(const float* __restrict__ src,
                                             u16* __restrict__ dst) {
  const int i = blockIdx.x * 256 + threadIdx.x;   // one float4 per thread
  const int row = i >> 9, col = (i & 511) << 2;   // 512 float4 per row
  const float4 v = reinterpret_cast<const float4*>(src)[i];
  ushort4 o;
  o.x = f2bf(v.x); o.y = f2bf(v.y); o.z = f2bf(v.z); o.w = f2bf(v.w);
  *reinterpret_cast<ushort4*>(dst + (size_t)row * DIN + swz(col, row)) = o;
}

// ---------------- transpose + convert + swizzle: src[R][C] f32 -> dst[C][R] bf16 ----------------
__global__ __launch_bounds__(256) void tcvt(const float* __restrict__ src,
                                            u16* __restrict__ dst,
                                            int R, int C, int dld) {
  __shared__ float tile[32][33];
  const int c0 = blockIdx.x * 32, r0 = blockIdx.y * 32;
  const int t = threadIdx.x;
  {
    const int rl = t >> 3, cl4 = (t & 7) * 4;
    const float4 v = *reinterpret_cast<const float4*>(src + (size_t)(r0 + rl) * C + c0 + cl4);
    tile[rl][cl4 + 0] = v.x; tile[rl][cl4 + 1] = v.y;
    tile[rl][cl4 + 2] = v.z; tile[rl][cl4 + 3] = v.w;
  }
  __syncthreads();
  {
    const int cl = t >> 3, rl4 = (t & 7) * 4;
    ushort4 o;
    o.x = f2bf(tile[rl4 + 0][cl]); o.y = f2bf(tile[rl4 + 1][cl]);
    o.z = f2bf(tile[rl4 + 2][cl]); o.w = f2bf(tile[rl4 + 3][cl]);
    const int rd = c0 + cl, cd = r0 + rl4;      // dst (row, col)
    *reinterpret_cast<ushort4*>(dst + (size_t)rd * dld + swz(cd, rd)) = o;
  }
}

// ---------------- bf16 GEMM, 128x128 tile, BK=64 (K|V proj + Wo GEMM) ----------------
// C[M][N] = A[M][K] @ Bt[N][K]^T ; A, Bt swz()-swizzled; C plain, leading dim ldc.
template <bool BF16_OUT>
__global__ __launch_bounds__(256) void gemm_bt(const u16* __restrict__ A,
                                               const u16* __restrict__ Bt,
                                               void* __restrict__ Cv,
                                               int M, int N, int K, int ldc) {
  __shared__ __align__(16) u16 As[128 * 64];
  __shared__ __align__(16) u16 Bs[128 * 64];
  const int tid = threadIdx.x, wv = tid >> 6, lane = tid & 63;
  const int m0 = blockIdx.y * 128, n0 = blockIdx.x * 128;
  const int wm = (wv >> 1) * 64, wn = (wv & 1) * 64;
  const int frow = lane & 15, quad = lane >> 4, fsw = frow & 7;
  const int srow = lane >> 3, scol = (lane & 7) * 8;
  floatx4 acc[4][4] = {};
  for (int k0 = 0; k0 < K; k0 += 64) {
#pragma unroll
    for (int i = 0; i < 4; ++i) {
      const int rr = (wv * 4 + i) * 8;
      gload_lds16(A  + (size_t)(m0 + rr + srow) * K + k0 + scol, &As[rr * 64]);
      gload_lds16(Bt + (size_t)(n0 + rr + srow) * K + k0 + scol, &Bs[rr * 64]);
    }
    __syncthreads();
#pragma unroll
    for (int ks = 0; ks < 2; ++ks) {
      bf16x8 af[4], bfr[4];
#pragma unroll
      for (int mi = 0; mi < 4; ++mi)
        af[mi] = *reinterpret_cast<const bf16x8*>(
            &As[(wm + mi * 16 + frow) * 64 + (((ks * 4 + quad) ^ fsw) << 3)]);
#pragma unroll
      for (int ni = 0; ni < 4; ++ni)
        bfr[ni] = *reinterpret_cast<const bf16x8*>(
            &Bs[(wn + ni * 16 + frow) * 64 + (((ks * 4 + quad) ^ fsw) << 3)]);
#pragma unroll
      for (int mi = 0; mi < 4; ++mi)
#pragma unroll
        for (int ni = 0; ni < 4; ++ni)
          acc[mi][ni] = __builtin_amdgcn_mfma_f32_16x16x32_bf16(af[mi], bfr[ni], acc[mi][ni], 0, 0, 0);
    }
    __syncthreads();
  }
  const int crow = (lane >> 4) * 4, ccol = lane & 15;
#pragma unroll
  for (int mi = 0; mi < 4; ++mi)
#pragma unroll
    for (int ni = 0; ni < 4; ++ni) {
      const size_t base = (size_t)(m0 + wm + mi * 16 + crow) * ldc + (n0 + wn + ni * 16 + ccol);
      if constexpr (BF16_OUT) {
        u16* C = (u16*)Cv;
#pragma unroll
        for (int r = 0; r < 4; ++r) C[base + (size_t)r * ldc] = f2bf(acc[mi][ni][r]);
      } else {
        float* C = (float*)Cv;
#pragma unroll
        for (int r = 0; r < 4; ++r) C[base + (size_t)r * ldc] = acc[mi][ni][r];
      }
    }
}

// ---------------- 8-phase deep-pipelined bf16 GEMM, 256x256 tile, BK=64 ----------------
// m201 geometry: 512 threads = 8 waves (2M x 4N), wave tile 128x64, acc[8][4]=128
// VGPR. 16 MFMA/phase. LDS 128 KiB (2 slots). Stage unit = 64 rows x 64 k;
// 8 units/tile, staged 3+3+2; counted vmcnt(3) at ph4/ph8 only.
// NOTE: no sched_barrier after lgkmcnt (m141: order-pinning regresses; rule #18
// applies only to inline-asm ds_reads, ours are compiler-visible).
__global__ __launch_bounds__(512, 2) void gemm256(const u16* __restrict__ A,
                                                  const u16* __restrict__ Bt,
                                                  u16* __restrict__ C,
                                                  int K, int ldc) {
  __shared__ __align__(16) u16 As[2][256 * 64];   // 64 KiB
  __shared__ __align__(16) u16 Bs[2][256 * 64];   // 64 KiB
  const int tid = threadIdx.x, wv = tid >> 6, lane = tid & 63;
  // XCD-bijective swizzle (grid = 256 WGs, multiple of 8)
  const int nx = gridDim.x;
  const int orig = blockIdx.y * nx + blockIdx.x;
  const int cpx = (nx * gridDim.y) >> 3;
  const int wgid = (orig & 7) * cpx + (orig >> 3);
  const int m0 = (wgid / nx) * 256, n0 = (wgid % nx) * 256;
  const int wm = (wv >> 2) * 128, wn = (wv & 3) * 64;
  const int f = lane & 15, quad = lane >> 4, fs = f & 7;

  const u16* Ab = A  + (size_t)(m0 + wv * 8 + (lane >> 3)) * K + (lane & 7) * 8;
  const u16* Bb = Bt + (size_t)(n0 + wv * 8 + (lane >> 3)) * K + (lane & 7) * 8;

  floatx4 acc[8][4] = {};
  bf16x8 af[4], bfr[4];

  auto stageA = [&](int sl, int t, int u) {
    gload_lds16(Ab + (size_t)u * 64 * K + (size_t)t * 64, &As[sl][(u * 64 + wv * 8) * 64]);
  };
  auto stageB = [&](int sl, int t, int u) {
    gload_lds16(Bb + (size_t)u * 64 * K + (size_t)t * 64, &Bs[sl][(u * 64 + wv * 8) * 64]);
  };
  auto loadA = [&](int sl, int fh, int ks) {
#pragma unroll
    for (int mf = 0; mf < 4; ++mf)
      af[mf] = *reinterpret_cast<const bf16x8*>(
          &As[sl][(wm + fh * 64 + mf * 16 + f) * 64 + ((((ks << 2) + quad) ^ fs) << 3)]);
  };
  auto loadB = [&](int sl, int ks) {
#pragma unroll
    for (int nf = 0; nf < 4; ++nf)
      bfr[nf] = *reinterpret_cast<const bf16x8*>(
          &Bs[sl][(wn + nf * 16 + f) * 64 + ((((ks << 2) + quad) ^ fs) << 3)]);
  };
  auto mmas = [&](int fh) {
#pragma unroll
    for (int mf = 0; mf < 4; ++mf)
#pragma unroll
      for (int nf = 0; nf < 4; ++nf)
        acc[fh * 4 + mf][nf] = __builtin_amdgcn_mfma_f32_16x16x32_bf16(
            af[mf], bfr[nf], acc[fh * 4 + mf][nf], 0, 0, 0);
  };

  // prologue: tile0 -> slot0 (8 units), then tile1 {A0,A2,B0} -> slot1 (in flight)
#pragma unroll
  for (int u = 0; u < 4; ++u) stageA(0, 0, u);
#pragma unroll
  for (int u = 0; u < 4; ++u) stageB(0, 0, u);
  stageA(1, 1, 0); stageA(1, 1, 2); stageB(1, 1, 0);
  asm volatile("s_waitcnt vmcnt(3)" ::: "memory");
  __builtin_amdgcn_s_barrier();

  const int IT = K >> 7;   // 2 K-tiles (BK=64 each) per iteration
#pragma unroll 1
  for (int i = 0; i < IT; ++i) {
    const int t0 = 2 * i;
    const bool st = (i < IT - 1);
    // ph1: slot0 (F0,k0); stage slot1(t0+1): A1,A3 (dead since end-ph8 prev), B1
    loadA(0, 0, 0); loadB(0, 0);
    stageA(1, t0 + 1, 1); stageA(1, t0 + 1, 3); stageB(1, t0 + 1, 1);
    __builtin_amdgcn_s_barrier();
    asm volatile("s_waitcnt lgkmcnt(0)" ::: "memory");
    __builtin_amdgcn_s_setprio(1); mmas(0); __builtin_amdgcn_s_setprio(0);
    __builtin_amdgcn_s_barrier();
    // ph2: slot0 (F1,k0); B(k0) frags reg-reused; stage slot1: B2,B3
    loadA(0, 1, 0);
    stageB(1, t0 + 1, 2); stageB(1, t0 + 1, 3);
    __builtin_amdgcn_s_barrier();
    asm volatile("s_waitcnt lgkmcnt(0)" ::: "memory");
    __builtin_amdgcn_s_setprio(1); mmas(1); __builtin_amdgcn_s_setprio(0);
    __builtin_amdgcn_s_barrier();
    // ph3: slot0 (F0,k1)  [last ds_reads of slot0 A0,A2 + all B]
    loadA(0, 0, 1); loadB(0, 1);
    __builtin_amdgcn_s_barrier();
    asm volatile("s_waitcnt lgkmcnt(0)" ::: "memory");
    __builtin_amdgcn_s_setprio(1); mmas(0); __builtin_amdgcn_s_setprio(0);
    __builtin_amdgcn_s_barrier();
    // ph4: slot0 (F1,k1); stage slot0'(t0+2): A0,A2,B0 (dead since end-ph3)
    // checkpoint: slot1(t0+1) fully landed (its last stage was ph2, 2 phases old)
    loadA(0, 1, 1);
    if (st) { stageA(0, t0 + 2, 0); stageA(0, t0 + 2, 2); stageB(0, t0 + 2, 0); }
    __builtin_amdgcn_s_barrier();
    asm volatile("s_waitcnt lgkmcnt(0)" ::: "memory");
    __builtin_amdgcn_s_setprio(1); mmas(1); __builtin_amdgcn_s_setprio(0);
    if (st) { asm volatile("s_waitcnt vmcnt(3)" ::: "memory"); }
    else    { asm volatile("s_waitcnt vmcnt(0)" ::: "memory"); }
    __builtin_amdgcn_s_barrier();
    // ph5: slot1 (F0,k0); stage slot0': A1,A3 (dead since end-ph4), B1
    loadA(1, 0, 0); loadB(1, 0);
    if (st) { stageA(0, t0 + 2, 1); stageA(0, t0 + 2, 3); stageB(0, t0 + 2, 1); }
    __builtin_amdgcn_s_barrier();
    asm volatile("s_waitcnt lgkmcnt(0)" ::: "memory");
    __builtin_amdgcn_s_setprio(1); mmas(0); __builtin_amdgcn_s_setprio(0);
    __builtin_amdgcn_s_barrier();
    // ph6: slot1 (F1,k0); stage slot0': B2,B3
    loadA(1, 1, 0);
    if (st) { stageB(0, t0 + 2, 2); stageB(0, t0 + 2, 3); }
    __builtin_amdgcn_s_barrier();
    asm volatile("s_waitcnt lgkmcnt(0)" ::: "memory");
    __builtin_amdgcn_s_setprio(1); mmas(1); __builtin_amdgcn_s_setprio(0);
    __builtin_amdgcn_s_barrier();
    // ph7: slot1 (F0,k1)  [last ds_reads of slot1 A0,A2 + all B]
    loadA(1, 0, 1); loadB(1, 1);
    __builtin_amdgcn_s_barrier();
    asm volatile("s_waitcnt lgkmcnt(0)" ::: "memory");
    __builtin_amdgcn_s_setprio(1); mmas(0); __builtin_amdgcn_s_setprio(0);
    __builtin_amdgcn_s_barrier();
    // ph8: slot1 (F1,k1); stage slot1''(t0+3): A0,A2,B0 (dead since end-ph7)
    // checkpoint: slot0'(t0+2) fully landed (its last stage was ph6, 2 phases old)
    loadA(1, 1, 1);
    if (st) { stageA(1, t0 + 3, 0); stageA(1, t0 + 3, 2); stageB(1, t0 + 3, 0); }
    __builtin_amdgcn_s_barrier();
    asm volatile("s_waitcnt lgkmcnt(0)" ::: "memory");
    __builtin_amdgcn_s_setprio(1); mmas(1); __builtin_amdgcn_s_setprio(0);
    if (st) { asm volatile("s_waitcnt vmcnt(3)" ::: "memory"); }
    __builtin_amdgcn_s_barrier();
  }

  // epilogue: plain bf16 C write (C/D layout: col = lane&15, row = quad*4 + r)
#pragma unroll
  for (int mf = 0; mf < 8; ++mf)
#pragma unroll
    for (int nf = 0; nf < 4; ++nf) {
      const size_t base = (size_t)(m0 + wm + (mf >> 2) * 64 + (mf & 3) * 16 + quad * 4) * ldc
                        + (n0 + wn + nf * 16 + f);
#pragma unroll
      for (int r = 0; r < 4; ++r) C[base + (size_t)r * ldc] = f2bf(acc[mf][nf][r]);
    }
}

// ---------------- fused RMSNorm + RoPE for Q (scale folded in), bf16 in ----------------
__global__ __launch_bounds__(256) void qnorm_rope(const u16* __restrict__ QKV,
                                                  const float* __restrict__ w,
                                                  const float* __restrict__ cosT,
                                                  const float* __restrict__ sinT,
                                                  u16* __restrict__ Qb) {
  const int wv = threadIdx.x >> 6, lane = threadIdx.x & 63;
  const int idx = blockIdx.x * 4 + wv;      // row*16 + h
  const int h = idx & 15, row = idx >> 4;   // row = b*S + s
  const int s = row & (S_LEN - 1), b = row >> 11;
  const u16* base = QKV + (size_t)row * DQKV + h * 256;
  const float v0 = bf2f(base[lane]), v1 = bf2f(base[lane + 64]);
  float ss = v0 * v0 + v1 * v1;
#pragma unroll
  for (int m = 32; m >= 1; m >>= 1) ss += __shfl_xor(ss, m);
  const float rn = rsqrtf(ss * (1.0f / 128.0f) + 1e-6f) * QK_SCALE;
  const float n0 = v0 * rn * (1.0f + w[lane]);
  const float n1 = v1 * rn * (1.0f + w[lane + 64]);
  const float c0 = cosT[(size_t)s * 128 + lane], c1 = cosT[(size_t)s * 128 + lane + 64];
  const float sn0 = sinT[(size_t)s * 128 + lane], sn1 = sinT[(size_t)s * 128 + lane + 64];
  u16* qb = Qb + ((size_t)(b * 16 + h) * S_LEN + s) * 128;
  qb[lane]      = f2bf(n0 * c0 - n1 * sn0);
  qb[lane + 64] = f2bf(n1 * c1 + n0 * sn1);
}

// ---------------- fused RMSNorm + RoPE for K, XOR-swizzled attn layout ----------------
__global__ __launch_bounds__(256) void knorm_rope(const u16* __restrict__ QKV,
                                                  const float* __restrict__ w,
                                                  const float* __restrict__ cosT,
                                                  const float* __restrict__ sinT,
                                                  u16* __restrict__ Kb) {
  const int wv = threadIdx.x >> 6, lane = threadIdx.x & 63;
  const int idx = blockIdx.x * 4 + wv;      // row*4 + g
  const int g = idx & 3, row = idx >> 2;
  const int s = row & (S_LEN - 1), b = row >> 11;
  const u16* base = QKV + (size_t)row * DQKV + DQG + g * 128;
  const float v0 = bf2f(base[lane]), v1 = bf2f(base[lane + 64]);
  float ss = v0 * v0 + v1 * v1;
#pragma unroll
  for (int m = 32; m >= 1; m >>= 1) ss += __shfl_xor(ss, m);
  const float rn = rsqrtf(ss * (1.0f / 128.0f) + 1e-6f);
  const float n0 = v0 * rn * (1.0f + w[lane]);
  const float n1 = v1 * rn * (1.0f + w[lane + 64]);
  const float c0 = cosT[(size_t)s * 128 + lane], c1 = cosT[(size_t)s * 128 + lane + 64];
  const float sn0 = sinT[(size_t)s * 128 + lane], sn1 = sinT[(size_t)s * 128 + lane + 64];
  u16* kb = Kb + ((size_t)(b * 4 + g) * S_LEN + s) * 128;
  const int sw = s & 7;
  const int d0 = lane, d1 = lane + 64;
  const int p0 = (((d0 >> 3) ^ sw) << 3) | (d0 & 7);
  const int p1 = (((d1 >> 3) ^ sw) << 3) | (d1 & 7);
  kb[p0] = f2bf(n0 * c0 - n1 * sn0);
  kb[p1] = f2bf(n1 * c1 + n0 * sn1);
}

// ---------------- V: QKV bf16 cols 4608.. -> Vt bf16 [bg][d][s], attn-swizzled ----------------
__global__ __launch_bounds__(256) void vtrans(const u16* __restrict__ QKV,
                                              u16* __restrict__ Vt) {
  __shared__ u16 tile[32][40];
  const int bg = blockIdx.z;                 // b*4+g
  const int s0 = blockIdx.x * 32, d0 = blockIdx.y * 32;
  const int b = bg >> 2, g = bg & 3;
  const int t = threadIdx.x;
  {
    const int sl = t >> 3, dl4 = (t & 7) * 4;
    const ushort4 v = *reinterpret_cast<const ushort4*>(
        QKV + (size_t)(b * S_LEN + s0 + sl) * DQKV + DQG + 512 + g * 128 + d0 + dl4);
    tile[sl][dl4 + 0] = v.x; tile[sl][dl4 + 1] = v.y;
    tile[sl][dl4 + 2] = v.z; tile[sl][dl4 + 3] = v.w;
  }
  __syncthreads();
  {
    const int dl = t >> 3, sl4 = (t & 7) * 4;
    ushort4 o;
    o.x = tile[sl4 + 0][dl]; o.y = tile[sl4 + 1][dl];
    o.z = tile[sl4 + 2][dl]; o.w = tile[sl4 + 3][dl];
    const int d = d0 + dl, s = s0 + sl4;
    const size_t base = (size_t)(bg * 128 + d) * S_LEN + (s & ~63);
    const int pos = ((((s >> 3) & 7) ^ (d & 7)) << 3) | (s & 7);
    *reinterpret_cast<ushort4*>(Vt + base + pos) = o;
  }
}

// ---------------- MFMA flash attention + gating (no-max softmax, paired causal) ----------------
// 2-phase double-buffered K/V staging (T3 minimum recipe): stage tile kt+1 at the
// top of iteration kt, compute slot[cur], single vmcnt(0)+barrier per tile.
// Staged slot was last read 1 iteration ago (sealed by that iteration's barrier).
// LDS 72.5 KiB -> 2 blocks/CU (unchanged occupancy vs single-buffer).
__global__ __launch_bounds__(256) void attn(const u16* __restrict__ Qb,
                                            const u16* __restrict__ Kb,
                                            const u16* __restrict__ Vt,
                                            const u16* __restrict__ QKV,
                                            u16* __restrict__ ctxg) {
  __shared__ __align__(16) u16 Ks[2][64 * 128];   // [slot][key][d], chunk-swizzled
  __shared__ __align__(16) u16 Vts[2][128 * 64];  // [slot][d][key], chunk-swizzled
  __shared__ __align__(16) u16 Ps[4][16 * 68];    // per-wave P [q][key], stride 68
  const int tid = threadIdx.x, wv = tid >> 6, lane = tid & 63;
  const int ip = blockIdx.x, bh = blockIdx.y;
  const int b = bh >> 4, h = bh & 15, g = h >> 2, bg = b * 4 + g;
  const int f = lane & 15, quad = lane >> 4, fq = quad * 8;
  const int fsw = f & 7;
  const u16* Kp = Kb + (size_t)bg * S_LEN * 128;
  const u16* Vp = Vt + (size_t)bg * 128 * S_LEN;
  u16* Pw = Ps[wv];

  auto stage_kv = [&](int sl, int kt) {
    const int k0 = kt * 64;
#pragma unroll
    for (int i = 0; i < 4; ++i) {
      const int j = wv * 4 + i;
      gload_lds16(Kp + (size_t)k0 * 128 + j * 512 + lane * 8, &Ks[sl][j * 512]);
    }
#pragma unroll
    for (int i = 0; i < 4; ++i) {
      const int r0 = (wv * 4 + i) * 8;
      gload_lds16(Vp + (size_t)(r0 + (lane >> 3)) * S_LEN + k0 + (lane & 7) * 8,
                  &Vts[sl][r0 * 64]);
    }
  };

  for (int pass = 0; pass < 2; ++pass) {
    const int qt = pass ? 31 - ip : ip;
    const u16* Qp = Qb + ((size_t)bh * S_LEN + qt * 64 + wv * 16) * 128;
    bf16x8 aq[4];
#pragma unroll
    for (int c = 0; c < 4; ++c)
      aq[c] = *reinterpret_cast<const bf16x8*>(&Qp[(size_t)f * 128 + c * 32 + fq]);

    floatx4 o[8] = {};
    float lsum[4] = {0.f, 0.f, 0.f, 0.f};
    const int nkt = qt + 1;

    // prologue: stage tile 0 -> slot 0
    stage_kv(0, 0);
    asm volatile("s_waitcnt vmcnt(0)" ::: "memory");
    __syncthreads();

    int cur = 0;
    for (int kt = 0; kt < nkt; ++kt) {
      const int k0 = kt * 64;
      // issue next tile's staging first -- it flies under this tile's compute
      if (kt + 1 < nkt) stage_kv(cur ^ 1, kt + 1);

      floatx4 sc[4] = {};
#pragma unroll
      for (int c = 0; c < 4; ++c) {
#pragma unroll
        for (int n = 0; n < 4; ++n) {
          bf16x8 bk = *reinterpret_cast<const bf16x8*>(
              &Ks[cur][(n * 16 + f) * 128 + (((4 * c + quad) ^ fsw) << 3)]);
          sc[n] = __builtin_amdgcn_mfma_f32_16x16x32_bf16(aq[c], bk, sc[n], 0, 0, 0);
        }
      }

      const int qrow0 = qt * 64 + wv * 16 + quad * 4;
#pragma unroll
      for (int n = 0; n < 4; ++n) {
        const int key = k0 + n * 16 + f;
#pragma unroll
        for (int r = 0; r < 4; ++r) {
          const float p = (key <= qrow0 + r) ? __expf(sc[n][r]) : 0.f;
          lsum[r] += p;
          Pw[(quad * 4 + r) * 68 + n * 16 + f] = f2bf(p);
        }
      }

#pragma unroll
      for (int kf = 0; kf < 2; ++kf) {
        bf16x8 pf = *reinterpret_cast<const bf16x8*>(&Pw[f * 68 + kf * 32 + fq]);
#pragma unroll
        for (int dt = 0; dt < 8; ++dt) {
          bf16x8 bv = *reinterpret_cast<const bf16x8*>(
              &Vts[cur][(dt * 16 + f) * 64 + (((4 * kf + quad) ^ fsw) << 3)]);
          o[dt] = __builtin_amdgcn_mfma_f32_16x16x32_bf16(pf, bv, o[dt], 0, 0, 0);
        }
      }

      // next tile fully landed (it had the whole compute phase to fly)
      asm volatile("s_waitcnt vmcnt(0)" ::: "memory");
      __syncthreads();
      cur ^= 1;
    }

#pragma unroll
    for (int r = 0; r < 4; ++r) {
#pragma unroll
      for (int mm = 8; mm >= 1; mm >>= 1) lsum[r] += __shfl_xor(lsum[r], mm);
    }

    // epilogue: 1/l, sigmoid gate (bf16), swizzled bf16 ctx write
#pragma unroll
    for (int r = 0; r < 4; ++r) {
      const int s = qt * 64 + wv * 16 + quad * 4 + r;
      const size_t grow = (size_t)b * S_LEN + s;
      const float inv = 1.0f / lsum[r];
#pragma unroll
      for (int dt = 0; dt < 8; ++dt) {
        const int d = dt * 16 + f;
        const float gate = bf2f(QKV[grow * DQKV + h * 256 + 128 + d]);
        const float val = o[dt][r] * inv * (1.0f / (1.0f + __expf(-gate)));
        const int col = h * 128 + d;
        ctxg[grow * 2048 + swz(col, (int)grow)] = f2bf(val);
      }
    }
  }
}

extern "C" void kernel_launch(void* const* d_in, const int* in_sizes, int n_in,
                              void* d_out, int out_size, void* d_ws, size_t ws_size,
                              hipStream_t stream) {
  const float* x    = (const float*)d_in[0];
  const float* Wq   = (const float*)d_in[1];
  const float* Wk   = (const float*)d_in[2];
  const float* Wv   = (const float*)d_in[3];
  const float* Wo   = (const float*)d_in[4];
  const float* qnw  = (const float*)d_in[5];
  const float* knw  = (const float*)d_in[6];
  const float* cosT = (const float*)d_in[7];
  const float* sinT = (const float*)d_in[8];
  // d_in[9] = mask (unused; causality computed analytically)

  char* p = (char*)d_ws;
  u16*   xb    = (u16*)p;  p += (size_t)NROWS * DIN * 2;       // x bf16 (swizzled)
  u16*   WqkvT = (u16*)p;  p += (size_t)DQKV * DIN * 2;        // [Wq|Wk|Wv]^T (swizzled)
  u16*   WoT   = (u16*)p;  p += (size_t)2048 * 2048 * 2;       // Wo^T (swizzled)
  u16*   QKVb  = (u16*)p;  p += (size_t)NROWS * DQKV * 2;      // qkv proj bf16 (plain)
  u16*   Qbf   = (u16*)p;  p += (size_t)2 * 16 * S_LEN * 128 * 2;
  u16*   Kbf   = (u16*)p;  p += (size_t)2 * 4 * S_LEN * 128 * 2;
  u16*   Vtb   = (u16*)p;  p += (size_t)2 * 4 * S_LEN * 128 * 2;
  u16*   ctxg  = (u16*)p;  p += (size_t)NROWS * 2048 * 2;      // gated ctx (swizzled)

  cvt_x<<<8192, 256, 0, stream>>>(x, xb);
  tcvt<<<dim3(128, 64), 256, 0, stream>>>(Wq, WqkvT, 2048, 4096, 2048);
  tcvt<<<dim3(16, 64), 256, 0, stream>>>(Wk, WqkvT + (size_t)4096 * 2048, 2048, 512, 2048);
  tcvt<<<dim3(16, 64), 256, 0, stream>>>(Wv, WqkvT + (size_t)4608 * 2048, 2048, 512, 2048);
  tcvt<<<dim3(64, 64), 256, 0, stream>>>(Wo, WoT, 2048, 2048, 2048);

  // Q|gate projection: 8-phase 256x256 pipeline, grid 16x16 = 256 WGs (1/CU, no tail)
  gemm256<<<dim3(16, 16), 512, 0, stream>>>(xb, WqkvT, QKVb, DIN, DQKV);
  // K|V projection: 128^2 tile, grid 8x32 = 256 WGs (1/CU, no tail)
  gemm_bt<true><<<dim3(8, 32), 256, 0, stream>>>(
      xb, WqkvT + (size_t)4096 * 2048, QKVb + 4096, NROWS, 1024, DIN, DQKV);

  qnorm_rope<<<16384, 256, 0, stream>>>(QKVb, qnw, cosT, sinT, Qbf);
  knorm_rope<<<4096, 256, 0, stream>>>(QKVb, knw, cosT, sinT, Kbf);
  vtrans<<<dim3(64, 4, 8), 256, 0, stream>>>(QKVb, Vtb);

  attn<<<dim3(16, 32), 256, 0, stream>>>(Qbf, Kbf, Vtb, QKVb, ctxg);

  gemm_bt<false><<<dim3(16, 32), 256, 0, stream>>>(ctxg, WoT, (float*)d_out, NROWS, 2048, 2048, 2048);
}

// Round 7
// 408.948 us; speedup vs baseline: 1.0364x; 1.0097x over previous
//
#include <hip/hip_runtime.h>

// Problem constants (B=2, S=2048, D_IN=2048, H=16, G=4, HD=128)
#define S_LEN 2048
#define NROWS 4096      // B*S
#define DIN   2048
#define DQKV  5120      // 4096 (q|gate) + 512 K + 512 V
#define DQG   4096

typedef __bf16 bf16x8 __attribute__((ext_vector_type(8)));
typedef float  floatx4 __attribute__((ext_vector_type(4)));
typedef unsigned short u16;

#define QK_SCALE 0.08838834764831845f   // 128^-0.5, folded into Q

__device__ __forceinline__ u16 f2bf(float f) {
  unsigned int u = __float_as_uint(f);
  u += 0x7fffu + ((u >> 16) & 1u);   // RNE
  return (u16)(u >> 16);
}
__device__ __forceinline__ float bf2f(u16 v) {
  return __uint_as_float(((unsigned int)v) << 16);
}
// XOR-8 chunk swizzle within each 64-element column group, keyed by row&7.
__device__ __forceinline__ int swz(int col, int row) {
  return (col & ~63) | ((((col >> 3) & 7) ^ (row & 7)) << 3) | (col & 7);
}

__device__ __forceinline__ void gload_lds16(const void* g, void* l) {
  __builtin_amdgcn_global_load_lds(
      (__attribute__((address_space(1))) void*)(void*)(g),
      (__attribute__((address_space(3))) void*)(l), 16, 0, 0);
}

// ---------------- x fp32 -> bf16, swizzled (C = 2048) ----------------
__global__ __launch_bounds__(256) void cvt_x(const float* __restrict__ src,
                                             u16* __restrict__ dst) {
  const int i = blockIdx.x * 256 + threadIdx.x;   // one float4 per thread
  const int row = i >> 9, col = (i & 511) << 2;   // 512 float4 per row
  const float4 v = reinterpret_cast<const float4*>(src)[i];
  ushort4 o;
  o.x = f2bf(v.x); o.y = f2bf(v.y); o.z = f2bf(v.z); o.w = f2bf(v.w);
  *reinterpret_cast<ushort4*>(dst + (size_t)row * DIN + swz(col, row)) = o;
}

// ---------------- transpose + convert + swizzle: src[R][C] f32 -> dst[C][R] bf16 ----------------
__global__ __launch_bounds__(256) void tcvt(const float* __restrict__ src,
                                            u16* __restrict__ dst,
                                            int R, int C, int dld) {
  __shared__ float tile[32][33];
  const int c0 = blockIdx.x * 32, r0 = blockIdx.y * 32;
  const int t = threadIdx.x;
  {
    const int rl = t >> 3, cl4 = (t & 7) * 4;
    const float4 v = *reinterpret_cast<const float4*>(src + (size_t)(r0 + rl) * C + c0 + cl4);
    tile[rl][cl4 + 0] = v.x; tile[rl][cl4 + 1] = v.y;
    tile[rl][cl4 + 2] = v.z; tile[rl][cl4 + 3] = v.w;
  }
  __syncthreads();
  {
    const int cl = t >> 3, rl4 = (t & 7) * 4;
    ushort4 o;
    o.x = f2bf(tile[rl4 + 0][cl]); o.y = f2bf(tile[rl4 + 1][cl]);
    o.z = f2bf(tile[rl4 + 2][cl]); o.w = f2bf(tile[rl4 + 3][cl]);
    const int rd = c0 + cl, cd = r0 + rl4;      // dst (row, col)
    *reinterpret_cast<ushort4*>(dst + (size_t)rd * dld + swz(cd, rd)) = o;
  }
}

// ---------------- bf16 GEMM, 128x128 tile, BK=64 (K|V proj + Wo GEMM) ----------------
// C[M][N] = A[M][K] @ Bt[N][K]^T ; A, Bt swz()-swizzled; C plain, leading dim ldc.
template <bool BF16_OUT>
__global__ __launch_bounds__(256) void gemm_bt(const u16* __restrict__ A,
                                               const u16* __restrict__ Bt,
                                               void* __restrict__ Cv,
                                               int M, int N, int K, int ldc) {
  __shared__ __align__(16) u16 As[128 * 64];
  __shared__ __align__(16) u16 Bs[128 * 64];
  const int tid = threadIdx.x, wv = tid >> 6, lane = tid & 63;
  const int m0 = blockIdx.y * 128, n0 = blockIdx.x * 128;
  const int wm = (wv >> 1) * 64, wn = (wv & 1) * 64;
  const int frow = lane & 15, quad = lane >> 4, fsw = frow & 7;
  const int srow = lane >> 3, scol = (lane & 7) * 8;
  floatx4 acc[4][4] = {};
  for (int k0 = 0; k0 < K; k0 += 64) {
#pragma unroll
    for (int i = 0; i < 4; ++i) {
      const int rr = (wv * 4 + i) * 8;
      gload_lds16(A  + (size_t)(m0 + rr + srow) * K + k0 + scol, &As[rr * 64]);
      gload_lds16(Bt + (size_t)(n0 + rr + srow) * K + k0 + scol, &Bs[rr * 64]);
    }
    __syncthreads();
#pragma unroll
    for (int ks = 0; ks < 2; ++ks) {
      bf16x8 af[4], bfr[4];
#pragma unroll
      for (int mi = 0; mi < 4; ++mi)
        af[mi] = *reinterpret_cast<const bf16x8*>(
            &As[(wm + mi * 16 + frow) * 64 + (((ks * 4 + quad) ^ fsw) << 3)]);
#pragma unroll
      for (int ni = 0; ni < 4; ++ni)
        bfr[ni] = *reinterpret_cast<const bf16x8*>(
            &Bs[(wn + ni * 16 + frow) * 64 + (((ks * 4 + quad) ^ fsw) << 3)]);
#pragma unroll
      for (int mi = 0; mi < 4; ++mi)
#pragma unroll
        for (int ni = 0; ni < 4; ++ni)
          acc[mi][ni] = __builtin_amdgcn_mfma_f32_16x16x32_bf16(af[mi], bfr[ni], acc[mi][ni], 0, 0, 0);
    }
    __syncthreads();
  }
  const int crow = (lane >> 4) * 4, ccol = lane & 15;
#pragma unroll
  for (int mi = 0; mi < 4; ++mi)
#pragma unroll
    for (int ni = 0; ni < 4; ++ni) {
      const size_t base = (size_t)(m0 + wm + mi * 16 + crow) * ldc + (n0 + wn + ni * 16 + ccol);
      if constexpr (BF16_OUT) {
        u16* C = (u16*)Cv;
#pragma unroll
        for (int r = 0; r < 4; ++r) C[base + (size_t)r * ldc] = f2bf(acc[mi][ni][r]);
      } else {
        float* C = (float*)Cv;
#pragma unroll
        for (int r = 0; r < 4; ++r) C[base + (size_t)r * ldc] = acc[mi][ni][r];
      }
    }
}

// ---------------- 8-phase deep-pipelined bf16 GEMM, 256x256 tile, BK=64 ----------------
// m201 geometry: 512 threads = 8 waves (2M x 4N), wave tile 128x64, acc[8][4]=128
// VGPR. 16 MFMA/phase. LDS 128 KiB (2 slots). Stage unit = 64 rows x 64 k;
// 8 units/tile, staged 3+3+2; counted vmcnt(3) at ph4/ph8 only.
__global__ __launch_bounds__(512, 2) void gemm256(const u16* __restrict__ A,
                                                  const u16* __restrict__ Bt,
                                                  u16* __restrict__ C,
                                                  int K, int ldc) {
  __shared__ __align__(16) u16 As[2][256 * 64];   // 64 KiB
  __shared__ __align__(16) u16 Bs[2][256 * 64];   // 64 KiB
  const int tid = threadIdx.x, wv = tid >> 6, lane = tid & 63;
  // XCD-bijective swizzle (grid = 256 WGs, multiple of 8)
  const int nx = gridDim.x;
  const int orig = blockIdx.y * nx + blockIdx.x;
  const int cpx = (nx * gridDim.y) >> 3;
  const int wgid = (orig & 7) * cpx + (orig >> 3);
  const int m0 = (wgid / nx) * 256, n0 = (wgid % nx) * 256;
  const int wm = (wv >> 2) * 128, wn = (wv & 3) * 64;
  const int f = lane & 15, quad = lane >> 4, fs = f & 7;

  const u16* Ab = A  + (size_t)(m0 + wv * 8 + (lane >> 3)) * K + (lane & 7) * 8;
  const u16* Bb = Bt + (size_t)(n0 + wv * 8 + (lane >> 3)) * K + (lane & 7) * 8;

  floatx4 acc[8][4] = {};
  bf16x8 af[4], bfr[4];

  auto stageA = [&](int sl, int t, int u) {
    gload_lds16(Ab + (size_t)u * 64 * K + (size_t)t * 64, &As[sl][(u * 64 + wv * 8) * 64]);
  };
  auto stageB = [&](int sl, int t, int u) {
    gload_lds16(Bb + (size_t)u * 64 * K + (size_t)t * 64, &Bs[sl][(u * 64 + wv * 8) * 64]);
  };
  auto loadA = [&](int sl, int fh, int ks) {
#pragma unroll
    for (int mf = 0; mf < 4; ++mf)
      af[mf] = *reinterpret_cast<const bf16x8*>(
          &As[sl][(wm + fh * 64 + mf * 16 + f) * 64 + ((((ks << 2) + quad) ^ fs) << 3)]);
  };
  auto loadB = [&](int sl, int ks) {
#pragma unroll
    for (int nf = 0; nf < 4; ++nf)
      bfr[nf] = *reinterpret_cast<const bf16x8*>(
          &Bs[sl][(wn + nf * 16 + f) * 64 + ((((ks << 2) + quad) ^ fs) << 3)]);
  };
  auto mmas = [&](int fh) {
#pragma unroll
    for (int mf = 0; mf < 4; ++mf)
#pragma unroll
      for (int nf = 0; nf < 4; ++nf)
        acc[fh * 4 + mf][nf] = __builtin_amdgcn_mfma_f32_16x16x32_bf16(
            af[mf], bfr[nf], acc[fh * 4 + mf][nf], 0, 0, 0);
  };

  // prologue: tile0 -> slot0 (8 units), then tile1 {A0,A2,B0} -> slot1 (in flight)
#pragma unroll
  for (int u = 0; u < 4; ++u) stageA(0, 0, u);
#pragma unroll
  for (int u = 0; u < 4; ++u) stageB(0, 0, u);
  stageA(1, 1, 0); stageA(1, 1, 2); stageB(1, 1, 0);
  asm volatile("s_waitcnt vmcnt(3)" ::: "memory");
  __builtin_amdgcn_s_barrier();

  const int IT = K >> 7;   // 2 K-tiles (BK=64 each) per iteration
#pragma unroll 1
  for (int i = 0; i < IT; ++i) {
    const int t0 = 2 * i;
    const bool st = (i < IT - 1);
    // ph1: slot0 (F0,k0); stage slot1(t0+1): A1,A3 (dead since end-ph8 prev), B1
    loadA(0, 0, 0); loadB(0, 0);
    stageA(1, t0 + 1, 1); stageA(1, t0 + 1, 3); stageB(1, t0 + 1, 1);
    __builtin_amdgcn_s_barrier();
    asm volatile("s_waitcnt lgkmcnt(0)" ::: "memory");
    __builtin_amdgcn_s_setprio(1); mmas(0); __builtin_amdgcn_s_setprio(0);
    __builtin_amdgcn_s_barrier();
    // ph2: slot0 (F1,k0); B(k0) frags reg-reused; stage slot1: B2,B3
    loadA(0, 1, 0);
    stageB(1, t0 + 1, 2); stageB(1, t0 + 1, 3);
    __builtin_amdgcn_s_barrier();
    asm volatile("s_waitcnt lgkmcnt(0)" ::: "memory");
    __builtin_amdgcn_s_setprio(1); mmas(1); __builtin_amdgcn_s_setprio(0);
    __builtin_amdgcn_s_barrier();
    // ph3: slot0 (F0,k1)  [last ds_reads of slot0 A0,A2 + all B]
    loadA(0, 0, 1); loadB(0, 1);
    __builtin_amdgcn_s_barrier();
    asm volatile("s_waitcnt lgkmcnt(0)" ::: "memory");
    __builtin_amdgcn_s_setprio(1); mmas(0); __builtin_amdgcn_s_setprio(0);
    __builtin_amdgcn_s_barrier();
    // ph4: slot0 (F1,k1); stage slot0'(t0+2): A0,A2,B0 (dead since end-ph3)
    loadA(0, 1, 1);
    if (st) { stageA(0, t0 + 2, 0); stageA(0, t0 + 2, 2); stageB(0, t0 + 2, 0); }
    __builtin_amdgcn_s_barrier();
    asm volatile("s_waitcnt lgkmcnt(0)" ::: "memory");
    __builtin_amdgcn_s_setprio(1); mmas(1); __builtin_amdgcn_s_setprio(0);
    if (st) { asm volatile("s_waitcnt vmcnt(3)" ::: "memory"); }
    else    { asm volatile("s_waitcnt vmcnt(0)" ::: "memory"); }
    __builtin_amdgcn_s_barrier();
    // ph5: slot1 (F0,k0); stage slot0': A1,A3 (dead since end-ph4), B1
    loadA(1, 0, 0); loadB(1, 0);
    if (st) { stageA(0, t0 + 2, 1); stageA(0, t0 + 2, 3); stageB(0, t0 + 2, 1); }
    __builtin_amdgcn_s_barrier();
    asm volatile("s_waitcnt lgkmcnt(0)" ::: "memory");
    __builtin_amdgcn_s_setprio(1); mmas(0); __builtin_amdgcn_s_setprio(0);
    __builtin_amdgcn_s_barrier();
    // ph6: slot1 (F1,k0); stage slot0': B2,B3
    loadA(1, 1, 0);
    if (st) { stageB(0, t0 + 2, 2); stageB(0, t0 + 2, 3); }
    __builtin_amdgcn_s_barrier();
    asm volatile("s_waitcnt lgkmcnt(0)" ::: "memory");
    __builtin_amdgcn_s_setprio(1); mmas(1); __builtin_amdgcn_s_setprio(0);
    __builtin_amdgcn_s_barrier();
    // ph7: slot1 (F0,k1)  [last ds_reads of slot1 A0,A2 + all B]
    loadA(1, 0, 1); loadB(1, 1);
    __builtin_amdgcn_s_barrier();
    asm volatile("s_waitcnt lgkmcnt(0)" ::: "memory");
    __builtin_amdgcn_s_setprio(1); mmas(0); __builtin_amdgcn_s_setprio(0);
    __builtin_amdgcn_s_barrier();
    // ph8: slot1 (F1,k1); stage slot1''(t0+3): A0,A2,B0 (dead since end-ph7)
    loadA(1, 1, 1);
    if (st) { stageA(1, t0 + 3, 0); stageA(1, t0 + 3, 2); stageB(1, t0 + 3, 0); }
    __builtin_amdgcn_s_barrier();
    asm volatile("s_waitcnt lgkmcnt(0)" ::: "memory");
    __builtin_amdgcn_s_setprio(1); mmas(1); __builtin_amdgcn_s_setprio(0);
    if (st) { asm volatile("s_waitcnt vmcnt(3)" ::: "memory"); }
    __builtin_amdgcn_s_barrier();
  }

  // epilogue: plain bf16 C write (C/D layout: col = lane&15, row = quad*4 + r)
#pragma unroll
  for (int mf = 0; mf < 8; ++mf)
#pragma unroll
    for (int nf = 0; nf < 4; ++nf) {
      const size_t base = (size_t)(m0 + wm + (mf >> 2) * 64 + (mf & 3) * 16 + quad * 4) * ldc
                        + (n0 + wn + nf * 16 + f);
#pragma unroll
      for (int r = 0; r < 4; ++r) C[base + (size_t)r * ldc] = f2bf(acc[mf][nf][r]);
    }
}

// ---------------- fused RMSNorm + RoPE for Q (scale folded in), bf16 in ----------------
__global__ __launch_bounds__(256) void qnorm_rope(const u16* __restrict__ QKV,
                                                  const float* __restrict__ w,
                                                  const float* __restrict__ cosT,
                                                  const float* __restrict__ sinT,
                                                  u16* __restrict__ Qb) {
  const int wv = threadIdx.x >> 6, lane = threadIdx.x & 63;
  const int idx = blockIdx.x * 4 + wv;      // row*16 + h
  const int h = idx & 15, row = idx >> 4;   // row = b*S + s
  const int s = row & (S_LEN - 1), b = row >> 11;
  const u16* base = QKV + (size_t)row * DQKV + h * 256;
  const float v0 = bf2f(base[lane]), v1 = bf2f(base[lane + 64]);
  float ss = v0 * v0 + v1 * v1;
#pragma unroll
  for (int m = 32; m >= 1; m >>= 1) ss += __shfl_xor(ss, m);
  const float rn = rsqrtf(ss * (1.0f / 128.0f) + 1e-6f) * QK_SCALE;
  const float n0 = v0 * rn * (1.0f + w[lane]);
  const float n1 = v1 * rn * (1.0f + w[lane + 64]);
  const float c0 = cosT[(size_t)s * 128 + lane], c1 = cosT[(size_t)s * 128 + lane + 64];
  const float sn0 = sinT[(size_t)s * 128 + lane], sn1 = sinT[(size_t)s * 128 + lane + 64];
  u16* qb = Qb + ((size_t)(b * 16 + h) * S_LEN + s) * 128;
  qb[lane]      = f2bf(n0 * c0 - n1 * sn0);
  qb[lane + 64] = f2bf(n1 * c1 + n0 * sn1);
}

// ---------------- fused RMSNorm + RoPE for K, XOR-swizzled attn layout ----------------
__global__ __launch_bounds__(256) void knorm_rope(const u16* __restrict__ QKV,
                                                  const float* __restrict__ w,
                                                  const float* __restrict__ cosT,
                                                  const float* __restrict__ sinT,
                                                  u16* __restrict__ Kb) {
  const int wv = threadIdx.x >> 6, lane = threadIdx.x & 63;
  const int idx = blockIdx.x * 4 + wv;      // row*4 + g
  const int g = idx & 3, row = idx >> 2;
  const int s = row & (S_LEN - 1), b = row >> 11;
  const u16* base = QKV + (size_t)row * DQKV + DQG + g * 128;
  const float v0 = bf2f(base[lane]), v1 = bf2f(base[lane + 64]);
  float ss = v0 * v0 + v1 * v1;
#pragma unroll
  for (int m = 32; m >= 1; m >>= 1) ss += __shfl_xor(ss, m);
  const float rn = rsqrtf(ss * (1.0f / 128.0f) + 1e-6f);
  const float n0 = v0 * rn * (1.0f + w[lane]);
  const float n1 = v1 * rn * (1.0f + w[lane + 64]);
  const float c0 = cosT[(size_t)s * 128 + lane], c1 = cosT[(size_t)s * 128 + lane + 64];
  const float sn0 = sinT[(size_t)s * 128 + lane], sn1 = sinT[(size_t)s * 128 + lane + 64];
  u16* kb = Kb + ((size_t)(b * 4 + g) * S_LEN + s) * 128;
  const int sw = s & 7;
  const int d0 = lane, d1 = lane + 64;
  const int p0 = (((d0 >> 3) ^ sw) << 3) | (d0 & 7);
  const int p1 = (((d1 >> 3) ^ sw) << 3) | (d1 & 7);
  kb[p0] = f2bf(n0 * c0 - n1 * sn0);
  kb[p1] = f2bf(n1 * c1 + n0 * sn1);
}

// ---------------- V: QKV bf16 cols 4608.. -> Vt bf16 [bg][d][s], attn-swizzled ----------------
__global__ __launch_bounds__(256) void vtrans(const u16* __restrict__ QKV,
                                              u16* __restrict__ Vt) {
  __shared__ u16 tile[32][40];
  const int bg = blockIdx.z;                 // b*4+g
  const int s0 = blockIdx.x * 32, d0 = blockIdx.y * 32;
  const int b = bg >> 2, g = bg & 3;
  const int t = threadIdx.x;
  {
    const int sl = t >> 3, dl4 = (t & 7) * 4;
    const ushort4 v = *reinterpret_cast<const ushort4*>(
        QKV + (size_t)(b * S_LEN + s0 + sl) * DQKV + DQG + 512 + g * 128 + d0 + dl4);
    tile[sl][dl4 + 0] = v.x; tile[sl][dl4 + 1] = v.y;
    tile[sl][dl4 + 2] = v.z; tile[sl][dl4 + 3] = v.w;
  }
  __syncthreads();
  {
    const int dl = t >> 3, sl4 = (t & 7) * 4;
    ushort4 o;
    o.x = tile[sl4 + 0][dl]; o.y = tile[sl4 + 1][dl];
    o.z = tile[sl4 + 2][dl]; o.w = tile[sl4 + 3][dl];
    const int d = d0 + dl, s = s0 + sl4;
    const size_t base = (size_t)(bg * 128 + d) * S_LEN + (s & ~63);
    const int pos = ((((s >> 3) & 7) ^ (d & 7)) << 3) | (s & 7);
    *reinterpret_cast<ushort4*>(Vt + base + pos) = o;
  }
}

// ---------------- MFMA flash attention + gating (swapped QK^T, pipelined) ----------------
// Swapped QK^T: sc = mfma(K_frag, Q_frag) -> lane (quad,f) holds P[q=f][key =
// n*16+quad*4+r] (A/B fragments are lane-symmetric, so LDS reads unchanged).
// P-write: 4x ds_write_b64 (was 16x b16); Ps stride 64 + XOR-chunk swizzle.
// Loop overlap: iter t = QK^T(t+1) MFMA -> pf(t) reads -> PV(t) MFMA || SM(t+1)
// VALU. K staged mid-iter (1-iter lead), V at iter end; counted vmcnt(4).
__global__ __launch_bounds__(256) void attn(const u16* __restrict__ Qb,
                                            const u16* __restrict__ Kb,
                                            const u16* __restrict__ Vt,
                                            const u16* __restrict__ QKV,
                                            u16* __restrict__ ctxg) {
  __shared__ __align__(16) u16 Ks[2][64 * 128];   // [slot][key][d], chunk-swizzled
  __shared__ __align__(16) u16 Vts[2][128 * 64];  // [slot][d][key], chunk-swizzled
  __shared__ __align__(16) u16 Ps[4][16 * 64];    // per-wave P [q=f][key], swizzled
  const int tid = threadIdx.x, wv = tid >> 6, lane = tid & 63;
  const int ip = blockIdx.x, bh = blockIdx.y;
  const int b = bh >> 4, h = bh & 15, g = h >> 2, bg = b * 4 + g;
  const int f = lane & 15, quad = lane >> 4, fq = quad * 8;
  const int fsw = f & 7;
  const u16* Kp = Kb + (size_t)bg * S_LEN * 128;
  const u16* Vp = Vt + (size_t)bg * 128 * S_LEN;
  u16* Pw = Ps[wv];
  // P addressing: write chunk (2n + quad>>1)^fsw, offset (quad&1)*4 (b64);
  // read chunk (4kf + quad)^fsw (b128).
  const int pwr_base = f * 64 + ((quad & 1) << 2);
  const int pf0_off = f * 64 + ((quad ^ fsw) << 3);
  const int pf1_off = f * 64 + (((4 + quad) ^ fsw) << 3);

  auto stage_k = [&](int sl, int kt) {
    const int k0 = kt * 64;
#pragma unroll
    for (int i = 0; i < 4; ++i) {
      const int j = wv * 4 + i;
      gload_lds16(Kp + (size_t)k0 * 128 + j * 512 + lane * 8, &Ks[sl][j * 512]);
    }
  };
  auto stage_v = [&](int sl, int kt) {
    const int k0 = kt * 64;
#pragma unroll
    for (int i = 0; i < 4; ++i) {
      const int r0 = (wv * 4 + i) * 8;
      gload_lds16(Vp + (size_t)(r0 + (lane >> 3)) * S_LEN + k0 + (lane & 7) * 8,
                  &Vts[sl][r0 * 64]);
    }
  };

  for (int pass = 0; pass < 2; ++pass) {
    const int qt = pass ? 31 - ip : ip;
    const int qrow = qt * 64 + wv * 16 + f;     // this lane's q-row (swapped layout)
    const u16* Qp = Qb + ((size_t)bh * S_LEN + qt * 64 + wv * 16) * 128;
    bf16x8 aq[4];
#pragma unroll
    for (int c = 0; c < 4; ++c)
      aq[c] = *reinterpret_cast<const bf16x8*>(&Qp[(size_t)f * 128 + c * 32 + fq]);

    floatx4 o[8] = {};
    float lsum = 0.f;
    const int nkt = qt + 1;

    // pass-boundary guard: previous pass's readers must leave the slots
    __syncthreads();
    // prologue staging: K0,V0[,K1,V1]
    stage_k(0, 0); stage_v(0, 0);
    if (nkt > 1) {
      stage_k(1, 1); stage_v(1, 1);
      asm volatile("s_waitcnt vmcnt(8)" ::: "memory");
    } else {
      asm volatile("s_waitcnt vmcnt(0)" ::: "memory");
    }
    __syncthreads();

    // QK^T(0) + SM(0) -> Pw
    {
      floatx4 sc[4] = {};
#pragma unroll
      for (int c = 0; c < 4; ++c)
#pragma unroll
        for (int n = 0; n < 4; ++n) {
          bf16x8 bk = *reinterpret_cast<const bf16x8*>(
              &Ks[0][(n * 16 + f) * 128 + (((4 * c + quad) ^ fsw) << 3)]);
          sc[n] = __builtin_amdgcn_mfma_f32_16x16x32_bf16(bk, aq[c], sc[n], 0, 0, 0);
        }
#pragma unroll
      for (int n = 0; n < 4; ++n) {
        float pv_[4];
#pragma unroll
        for (int r = 0; r < 4; ++r) {
          const int key = n * 16 + quad * 4 + r;
          const float p = (key <= qrow) ? __expf(sc[n][r]) : 0.f;
          lsum += p; pv_[r] = p;
        }
        ushort4 pk;
        pk.x = f2bf(pv_[0]); pk.y = f2bf(pv_[1]); pk.z = f2bf(pv_[2]); pk.w = f2bf(pv_[3]);
        *reinterpret_cast<ushort4*>(
            &Pw[pwr_base + (((2 * n + (quad >> 1)) ^ fsw) << 3)]) = pk;
      }
    }
    if (nkt > 1) {
      asm volatile("s_waitcnt vmcnt(4)" ::: "memory");   // K1 landed (V1 in flight)
      __syncthreads();
    }

    int cur = 0;
    for (int t = 0; t < nkt; ++t) {
      const bool more = (t + 1 < nkt);
      floatx4 sn[4] = {};
      if (more) {
        // QK^T(t+1) from Ks[cur^1] (landed: prev iter's vmcnt+barrier)
#pragma unroll
        for (int c = 0; c < 4; ++c)
#pragma unroll
          for (int n = 0; n < 4; ++n) {
            bf16x8 bk = *reinterpret_cast<const bf16x8*>(
                &Ks[cur ^ 1][(n * 16 + f) * 128 + (((4 * c + quad) ^ fsw) << 3)]);
            sn[n] = __builtin_amdgcn_mfma_f32_16x16x32_bf16(bk, aq[c], sn[n], 0, 0, 0);
          }
        if (t + 2 < nkt) stage_k(cur, t + 2);   // K(t) slot dead since prev iter
      }
      // read tile t's P fragments (before SM(t+1) overwrites Pw; wave-local, in-order LDS)
      bf16x8 pf0 = *reinterpret_cast<const bf16x8*>(&Pw[pf0_off]);
      bf16x8 pf1 = *reinterpret_cast<const bf16x8*>(&Pw[pf1_off]);
      // PV(t)  (MFMA; independent of SM(t+1) VALU below -> co-scheduled)
#pragma unroll
      for (int dt = 0; dt < 8; ++dt) {
        bf16x8 bv = *reinterpret_cast<const bf16x8*>(
            &Vts[cur][(dt * 16 + f) * 64 + ((quad ^ fsw) << 3)]);
        o[dt] = __builtin_amdgcn_mfma_f32_16x16x32_bf16(pf0, bv, o[dt], 0, 0, 0);
      }
#pragma unroll
      for (int dt = 0; dt < 8; ++dt) {
        bf16x8 bv = *reinterpret_cast<const bf16x8*>(
            &Vts[cur][(dt * 16 + f) * 64 + (((4 + quad) ^ fsw) << 3)]);
        o[dt] = __builtin_amdgcn_mfma_f32_16x16x32_bf16(pf1, bv, o[dt], 0, 0, 0);
      }
      if (more) {
        // SM(t+1) -> Pw
        const int kb = (t + 1) * 64;
#pragma unroll
        for (int n = 0; n < 4; ++n) {
          float pv_[4];
#pragma unroll
          for (int r = 0; r < 4; ++r) {
            const int key = kb + n * 16 + quad * 4 + r;
            const float p = (key <= qrow) ? __expf(sn[n][r]) : 0.f;
            lsum += p; pv_[r] = p;
          }
          ushort4 pk;
          pk.x = f2bf(pv_[0]); pk.y = f2bf(pv_[1]); pk.z = f2bf(pv_[2]); pk.w = f2bf(pv_[3]);
          *reinterpret_cast<ushort4*>(
              &Pw[pwr_base + (((2 * n + (quad >> 1)) ^ fsw) << 3)]) = pk;
        }
        __syncthreads();                        // all waves done reading Vts[cur]
        if (t + 2 < nkt) {
          stage_v(cur, t + 2);                  // V(t) dead (read above)
          asm volatile("s_waitcnt vmcnt(4)" ::: "memory");  // V(t+1)+K(t+2) landed
        } else {
          asm volatile("s_waitcnt vmcnt(0)" ::: "memory");  // V(t+1) landed
        }
        __syncthreads();
        cur ^= 1;
      }
    }

    // row-sum across quads (row f held by lanes f, f+16, f+32, f+48)
    lsum += __shfl_xor(lsum, 16);
    lsum += __shfl_xor(lsum, 32);
    const float inv = 1.0f / lsum;

    // epilogue: rows quad*4+r; row sums live keyed by f -> broadcast from lanes 0..15
#pragma unroll
    for (int r = 0; r < 4; ++r) {
      const float linv = __shfl(inv, quad * 4 + r);
      const int s = qt * 64 + wv * 16 + quad * 4 + r;
      const size_t grow = (size_t)b * S_LEN + s;
#pragma unroll
      for (int dt = 0; dt < 8; ++dt) {
        const int d = dt * 16 + f;
        const float gate = bf2f(QKV[grow * DQKV + h * 256 + 128 + d]);
        const float val = o[dt][r] * linv * (1.0f / (1.0f + __expf(-gate)));
        const int col = h * 128 + d;
        ctxg[grow * 2048 + swz(col, (int)grow)] = f2bf(val);
      }
    }
  }
}

extern "C" void kernel_launch(void* const* d_in, const int* in_sizes, int n_in,
                              void* d_out, int out_size, void* d_ws, size_t ws_size,
                              hipStream_t stream) {
  const float* x    = (const float*)d_in[0];
  const float* Wq   = (const float*)d_in[1];
  const float* Wk   = (const float*)d_in[2];
  const float* Wv   = (const float*)d_in[3];
  const float* Wo   = (const float*)d_in[4];
  const float* qnw  = (const float*)d_in[5];
  const float* knw  = (const float*)d_in[6];
  const float* cosT = (const float*)d_in[7];
  const float* sinT = (const float*)d_in[8];
  // d_in[9] = mask (unused; causality computed analytically)

  char* p = (char*)d_ws;
  u16*   xb    = (u16*)p;  p += (size_t)NROWS * DIN * 2;       // x bf16 (swizzled)
  u16*   WqkvT = (u16*)p;  p += (size_t)DQKV * DIN * 2;        // [Wq|Wk|Wv]^T (swizzled)
  u16*   WoT   = (u16*)p;  p += (size_t)2048 * 2048 * 2;       // Wo^T (swizzled)
  u16*   QKVb  = (u16*)p;  p += (size_t)NROWS * DQKV * 2;      // qkv proj bf16 (plain)
  u16*   Qbf   = (u16*)p;  p += (size_t)2 * 16 * S_LEN * 128 * 2;
  u16*   Kbf   = (u16*)p;  p += (size_t)2 * 4 * S_LEN * 128 * 2;
  u16*   Vtb   = (u16*)p;  p += (size_t)2 * 4 * S_LEN * 128 * 2;
  u16*   ctxg  = (u16*)p;  p += (size_t)NROWS * 2048 * 2;      // gated ctx (swizzled)

  cvt_x<<<8192, 256, 0, stream>>>(x, xb);
  tcvt<<<dim3(128, 64), 256, 0, stream>>>(Wq, WqkvT, 2048, 4096, 2048);
  tcvt<<<dim3(16, 64), 256, 0, stream>>>(Wk, WqkvT + (size_t)4096 * 2048, 2048, 512, 2048);
  tcvt<<<dim3(16, 64), 256, 0, stream>>>(Wv, WqkvT + (size_t)4608 * 2048, 2048, 512, 2048);
  tcvt<<<dim3(64, 64), 256, 0, stream>>>(Wo, WoT, 2048, 2048, 2048);

  // Q|gate projection: 8-phase 256x256 pipeline, grid 16x16 = 256 WGs (1/CU, no tail)
  gemm256<<<dim3(16, 16), 512, 0, stream>>>(xb, WqkvT, QKVb, DIN, DQKV);
  // K|V projection: 128^2 tile, grid 8x32 = 256 WGs (1/CU, no tail)
  gemm_bt<true><<<dim3(8, 32), 256, 0, stream>>>(
      xb, WqkvT + (size_t)4096 * 2048, QKVb + 4096, NROWS, 1024, DIN, DQKV);

  qnorm_rope<<<16384, 256, 0, stream>>>(QKVb, qnw, cosT, sinT, Qbf);
  knorm_rope<<<4096, 256, 0, stream>>>(QKVb, knw, cosT, sinT, Kbf);
  vtrans<<<dim3(64, 4, 8), 256, 0, stream>>>(QKVb, Vtb);

  attn<<<dim3(16, 32), 256, 0, stream>>>(Qbf, Kbf, Vtb, QKVb, ctxg);

  gemm_bt<false><<<dim3(16, 32), 256, 0, stream>>>(ctxg, WoT, (float*)d_out, NROWS, 2048, 2048, 2048);
}

// Round 8
// 393.109 us; speedup vs baseline: 1.0782x; 1.0403x over previous
//
#include <hip/hip_runtime.h>

// Problem constants (B=2, S=2048, D_IN=2048, H=16, G=4, HD=128)
#define S_LEN 2048
#define NROWS 4096      // B*S
#define DIN   2048
#define DQKV  5120      // 4096 (q|gate) + 512 K + 512 V
#define DQG   4096

typedef __bf16 bf16x8 __attribute__((ext_vector_type(8)));
typedef float  floatx4 __attribute__((ext_vector_type(4)));
typedef unsigned short u16;

#define QK_SCALE 0.08838834764831845f   // 128^-0.5, folded into Q

__device__ __forceinline__ u16 f2bf(float f) {
  unsigned int u = __float_as_uint(f);
  u += 0x7fffu + ((u >> 16) & 1u);   // RNE
  return (u16)(u >> 16);
}
__device__ __forceinline__ float bf2f(u16 v) {
  return __uint_as_float(((unsigned int)v) << 16);
}
// XOR-8 chunk swizzle within each 64-element column group, keyed by row&7.
__device__ __forceinline__ int swz(int col, int row) {
  return (col & ~63) | ((((col >> 3) & 7) ^ (row & 7)) << 3) | (col & 7);
}

__device__ __forceinline__ void gload_lds16(const void* g, void* l) {
  __builtin_amdgcn_global_load_lds(
      (__attribute__((address_space(1))) void*)(void*)(g),
      (__attribute__((address_space(3))) void*)(l), 16, 0, 0);
}

// ---------------- merged preprocessing: x-cvt + 4 transposes (1 launch) ----------------
// ranges: [0,8192) cvt_x | [8192,16384) Wq^T | [16384,17408) Wk^T |
//         [17408,18432) Wv^T | [18432,22528) Wo^T
__device__ __forceinline__ void tcvt_body(const float* __restrict__ src,
                                          u16* __restrict__ dst,
                                          int C, int dld, int bx, int by,
                                          float (*tile)[33]) {
  const int c0 = bx * 32, r0 = by * 32;
  const int t = threadIdx.x;
  {
    const int rl = t >> 3, cl4 = (t & 7) * 4;
    const float4 v = *reinterpret_cast<const float4*>(src + (size_t)(r0 + rl) * C + c0 + cl4);
    tile[rl][cl4 + 0] = v.x; tile[rl][cl4 + 1] = v.y;
    tile[rl][cl4 + 2] = v.z; tile[rl][cl4 + 3] = v.w;
  }
  __syncthreads();
  {
    const int cl = t >> 3, rl4 = (t & 7) * 4;
    ushort4 o;
    o.x = f2bf(tile[rl4 + 0][cl]); o.y = f2bf(tile[rl4 + 1][cl]);
    o.z = f2bf(tile[rl4 + 2][cl]); o.w = f2bf(tile[rl4 + 3][cl]);
    const int rd = c0 + cl, cd = r0 + rl4;      // dst (row, col)
    *reinterpret_cast<ushort4*>(dst + (size_t)rd * dld + swz(cd, rd)) = o;
  }
}

__global__ __launch_bounds__(256) void prep(const float* __restrict__ x,
                                            const float* __restrict__ Wq,
                                            const float* __restrict__ Wk,
                                            const float* __restrict__ Wv,
                                            const float* __restrict__ Wo,
                                            u16* __restrict__ xb,
                                            u16* __restrict__ WqkvT,
                                            u16* __restrict__ WoT) {
  __shared__ float tile[32][33];
  const int bid = blockIdx.x;
  if (bid < 8192) {                       // cvt_x
    const int i = bid * 256 + threadIdx.x;
    const int row = i >> 9, col = (i & 511) << 2;
    const float4 v = reinterpret_cast<const float4*>(x)[i];
    ushort4 o;
    o.x = f2bf(v.x); o.y = f2bf(v.y); o.z = f2bf(v.z); o.w = f2bf(v.w);
    *reinterpret_cast<ushort4*>(xb + (size_t)row * DIN + swz(col, row)) = o;
  } else if (bid < 16384) {               // Wq^T (2048x4096 -> rows 0..4095)
    const int l = bid - 8192;
    tcvt_body(Wq, WqkvT, 4096, 2048, l & 127, l >> 7, tile);
  } else if (bid < 17408) {               // Wk^T -> rows 4096..4607
    const int l = bid - 16384;
    tcvt_body(Wk, WqkvT + (size_t)4096 * 2048, 512, 2048, l & 15, l >> 4, tile);
  } else if (bid < 18432) {               // Wv^T -> rows 4608..5119
    const int l = bid - 17408;
    tcvt_body(Wv, WqkvT + (size_t)4608 * 2048, 512, 2048, l & 15, l >> 4, tile);
  } else {                                // Wo^T
    const int l = bid - 18432;
    tcvt_body(Wo, WoT, 2048, 2048, l & 63, l >> 6, tile);
  }
}

// ---------------- bf16 GEMM, 128x128 tile, BK=64 (K|V proj + Wo GEMM) ----------------
// C[M][N] = A[M][K] @ Bt[N][K]^T ; A, Bt swz()-swizzled; C plain, leading dim ldc.
template <bool BF16_OUT>
__global__ __launch_bounds__(256) void gemm_bt(const u16* __restrict__ A,
                                               const u16* __restrict__ Bt,
                                               void* __restrict__ Cv,
                                               int M, int N, int K, int ldc) {
  __shared__ __align__(16) u16 As[128 * 64];
  __shared__ __align__(16) u16 Bs[128 * 64];
  const int tid = threadIdx.x, wv = tid >> 6, lane = tid & 63;
  const int m0 = blockIdx.y * 128, n0 = blockIdx.x * 128;
  const int wm = (wv >> 1) * 64, wn = (wv & 1) * 64;
  const int frow = lane & 15, quad = lane >> 4, fsw = frow & 7;
  const int srow = lane >> 3, scol = (lane & 7) * 8;
  floatx4 acc[4][4] = {};
  for (int k0 = 0; k0 < K; k0 += 64) {
#pragma unroll
    for (int i = 0; i < 4; ++i) {
      const int rr = (wv * 4 + i) * 8;
      gload_lds16(A  + (size_t)(m0 + rr + srow) * K + k0 + scol, &As[rr * 64]);
      gload_lds16(Bt + (size_t)(n0 + rr + srow) * K + k0 + scol, &Bs[rr * 64]);
    }
    __syncthreads();
#pragma unroll
    for (int ks = 0; ks < 2; ++ks) {
      bf16x8 af[4], bfr[4];
#pragma unroll
      for (int mi = 0; mi < 4; ++mi)
        af[mi] = *reinterpret_cast<const bf16x8*>(
            &As[(wm + mi * 16 + frow) * 64 + (((ks * 4 + quad) ^ fsw) << 3)]);
#pragma unroll
      for (int ni = 0; ni < 4; ++ni)
        bfr[ni] = *reinterpret_cast<const bf16x8*>(
            &Bs[(wn + ni * 16 + frow) * 64 + (((ks * 4 + quad) ^ fsw) << 3)]);
#pragma unroll
      for (int mi = 0; mi < 4; ++mi)
#pragma unroll
        for (int ni = 0; ni < 4; ++ni)
          acc[mi][ni] = __builtin_amdgcn_mfma_f32_16x16x32_bf16(af[mi], bfr[ni], acc[mi][ni], 0, 0, 0);
    }
    __syncthreads();
  }
  const int crow = (lane >> 4) * 4, ccol = lane & 15;
#pragma unroll
  for (int mi = 0; mi < 4; ++mi)
#pragma unroll
    for (int ni = 0; ni < 4; ++ni) {
      const size_t base = (size_t)(m0 + wm + mi * 16 + crow) * ldc + (n0 + wn + ni * 16 + ccol);
      if constexpr (BF16_OUT) {
        u16* C = (u16*)Cv;
#pragma unroll
        for (int r = 0; r < 4; ++r) C[base + (size_t)r * ldc] = f2bf(acc[mi][ni][r]);
      } else {
        float* C = (float*)Cv;
#pragma unroll
        for (int r = 0; r < 4; ++r) C[base + (size_t)r * ldc] = acc[mi][ni][r];
      }
    }
}

// ---------------- 8-phase deep-pipelined bf16 GEMM, 256x256 tile, BK=64 ----------------
// (unchanged from round 7 — 84 µs / 34% MfmaUtil measured; held constant this round)
__global__ __launch_bounds__(512, 2) void gemm256(const u16* __restrict__ A,
                                                  const u16* __restrict__ Bt,
                                                  u16* __restrict__ C,
                                                  int K, int ldc) {
  __shared__ __align__(16) u16 As[2][256 * 64];   // 64 KiB
  __shared__ __align__(16) u16 Bs[2][256 * 64];   // 64 KiB
  const int tid = threadIdx.x, wv = tid >> 6, lane = tid & 63;
  const int nx = gridDim.x;
  const int orig = blockIdx.y * nx + blockIdx.x;
  const int cpx = (nx * gridDim.y) >> 3;
  const int wgid = (orig & 7) * cpx + (orig >> 3);
  const int m0 = (wgid / nx) * 256, n0 = (wgid % nx) * 256;
  const int wm = (wv >> 2) * 128, wn = (wv & 3) * 64;
  const int f = lane & 15, quad = lane >> 4, fs = f & 7;

  const u16* Ab = A  + (size_t)(m0 + wv * 8 + (lane >> 3)) * K + (lane & 7) * 8;
  const u16* Bb = Bt + (size_t)(n0 + wv * 8 + (lane >> 3)) * K + (lane & 7) * 8;

  floatx4 acc[8][4] = {};
  bf16x8 af[4], bfr[4];

  auto stageA = [&](int sl, int t, int u) {
    gload_lds16(Ab + (size_t)u * 64 * K + (size_t)t * 64, &As[sl][(u * 64 + wv * 8) * 64]);
  };
  auto stageB = [&](int sl, int t, int u) {
    gload_lds16(Bb + (size_t)u * 64 * K + (size_t)t * 64, &Bs[sl][(u * 64 + wv * 8) * 64]);
  };
  auto loadA = [&](int sl, int fh, int ks) {
#pragma unroll
    for (int mf = 0; mf < 4; ++mf)
      af[mf] = *reinterpret_cast<const bf16x8*>(
          &As[sl][(wm + fh * 64 + mf * 16 + f) * 64 + ((((ks << 2) + quad) ^ fs) << 3)]);
  };
  auto loadB = [&](int sl, int ks) {
#pragma unroll
    for (int nf = 0; nf < 4; ++nf)
      bfr[nf] = *reinterpret_cast<const bf16x8*>(
          &Bs[sl][(wn + nf * 16 + f) * 64 + ((((ks << 2) + quad) ^ fs) << 3)]);
  };
  auto mmas = [&](int fh) {
#pragma unroll
    for (int mf = 0; mf < 4; ++mf)
#pragma unroll
      for (int nf = 0; nf < 4; ++nf)
        acc[fh * 4 + mf][nf] = __builtin_amdgcn_mfma_f32_16x16x32_bf16(
            af[mf], bfr[nf], acc[fh * 4 + mf][nf], 0, 0, 0);
  };

  // prologue: tile0 -> slot0 (8 units), then tile1 {A0,A2,B0} -> slot1 (in flight)
#pragma unroll
  for (int u = 0; u < 4; ++u) stageA(0, 0, u);
#pragma unroll
  for (int u = 0; u < 4; ++u) stageB(0, 0, u);
  stageA(1, 1, 0); stageA(1, 1, 2); stageB(1, 1, 0);
  asm volatile("s_waitcnt vmcnt(3)" ::: "memory");
  __builtin_amdgcn_s_barrier();

  const int IT = K >> 7;   // 2 K-tiles (BK=64 each) per iteration
#pragma unroll 1
  for (int i = 0; i < IT; ++i) {
    const int t0 = 2 * i;
    const bool st = (i < IT - 1);
    // ph1
    loadA(0, 0, 0); loadB(0, 0);
    stageA(1, t0 + 1, 1); stageA(1, t0 + 1, 3); stageB(1, t0 + 1, 1);
    __builtin_amdgcn_s_barrier();
    asm volatile("s_waitcnt lgkmcnt(0)" ::: "memory");
    __builtin_amdgcn_s_setprio(1); mmas(0); __builtin_amdgcn_s_setprio(0);
    __builtin_amdgcn_s_barrier();
    // ph2
    loadA(0, 1, 0);
    stageB(1, t0 + 1, 2); stageB(1, t0 + 1, 3);
    __builtin_amdgcn_s_barrier();
    asm volatile("s_waitcnt lgkmcnt(0)" ::: "memory");
    __builtin_amdgcn_s_setprio(1); mmas(1); __builtin_amdgcn_s_setprio(0);
    __builtin_amdgcn_s_barrier();
    // ph3
    loadA(0, 0, 1); loadB(0, 1);
    __builtin_amdgcn_s_barrier();
    asm volatile("s_waitcnt lgkmcnt(0)" ::: "memory");
    __builtin_amdgcn_s_setprio(1); mmas(0); __builtin_amdgcn_s_setprio(0);
    __builtin_amdgcn_s_barrier();
    // ph4
    loadA(0, 1, 1);
    if (st) { stageA(0, t0 + 2, 0); stageA(0, t0 + 2, 2); stageB(0, t0 + 2, 0); }
    __builtin_amdgcn_s_barrier();
    asm volatile("s_waitcnt lgkmcnt(0)" ::: "memory");
    __builtin_amdgcn_s_setprio(1); mmas(1); __builtin_amdgcn_s_setprio(0);
    if (st) { asm volatile("s_waitcnt vmcnt(3)" ::: "memory"); }
    else    { asm volatile("s_waitcnt vmcnt(0)" ::: "memory"); }
    __builtin_amdgcn_s_barrier();
    // ph5
    loadA(1, 0, 0); loadB(1, 0);
    if (st) { stageA(0, t0 + 2, 1); stageA(0, t0 + 2, 3); stageB(0, t0 + 2, 1); }
    __builtin_amdgcn_s_barrier();
    asm volatile("s_waitcnt lgkmcnt(0)" ::: "memory");
    __builtin_amdgcn_s_setprio(1); mmas(0); __builtin_amdgcn_s_setprio(0);
    __builtin_amdgcn_s_barrier();
    // ph6
    loadA(1, 1, 0);
    if (st) { stageB(0, t0 + 2, 2); stageB(0, t0 + 2, 3); }
    __builtin_amdgcn_s_barrier();
    asm volatile("s_waitcnt lgkmcnt(0)" ::: "memory");
    __builtin_amdgcn_s_setprio(1); mmas(1); __builtin_amdgcn_s_setprio(0);
    __builtin_amdgcn_s_barrier();
    // ph7
    loadA(1, 0, 1); loadB(1, 1);
    __builtin_amdgcn_s_barrier();
    asm volatile("s_waitcnt lgkmcnt(0)" ::: "memory");
    __builtin_amdgcn_s_setprio(1); mmas(0); __builtin_amdgcn_s_setprio(0);
    __builtin_amdgcn_s_barrier();
    // ph8
    loadA(1, 1, 1);
    if (st) { stageA(1, t0 + 3, 0); stageA(1, t0 + 3, 2); stageB(1, t0 + 3, 0); }
    __builtin_amdgcn_s_barrier();
    asm volatile("s_waitcnt lgkmcnt(0)" ::: "memory");
    __builtin_amdgcn_s_setprio(1); mmas(1); __builtin_amdgcn_s_setprio(0);
    if (st) { asm volatile("s_waitcnt vmcnt(3)" ::: "memory"); }
    __builtin_amdgcn_s_barrier();
  }

  // epilogue
#pragma unroll
  for (int mf = 0; mf < 8; ++mf)
#pragma unroll
    for (int nf = 0; nf < 4; ++nf) {
      const size_t base = (size_t)(m0 + wm + (mf >> 2) * 64 + (mf & 3) * 16 + quad * 4) * ldc
                        + (n0 + wn + nf * 16 + f);
#pragma unroll
      for (int r = 0; r < 4; ++r) C[base + (size_t)r * ldc] = f2bf(acc[mf][nf][r]);
    }
}

// ---------------- merged post-projection: qnorm_rope + knorm_rope + vtrans (1 launch) ----------------
// ranges: [0,16384) qnorm | [16384,20480) knorm | [20480,22528) vtrans
__global__ __launch_bounds__(256) void postproj(const u16* __restrict__ QKV,
                                                const float* __restrict__ qw,
                                                const float* __restrict__ kw,
                                                const float* __restrict__ cosT,
                                                const float* __restrict__ sinT,
                                                u16* __restrict__ Qb,
                                                u16* __restrict__ Kb,
                                                u16* __restrict__ Vt) {
  __shared__ u16 tile[32][40];
  const int bid = blockIdx.x;
  const int wv = threadIdx.x >> 6, lane = threadIdx.x & 63;
  if (bid < 16384) {                      // qnorm_rope
    const int idx = bid * 4 + wv;         // row*16 + h
    const int h = idx & 15, row = idx >> 4;
    const int s = row & (S_LEN - 1), b = row >> 11;
    const u16* base = QKV + (size_t)row * DQKV + h * 256;
    const float v0 = bf2f(base[lane]), v1 = bf2f(base[lane + 64]);
    float ss = v0 * v0 + v1 * v1;
#pragma unroll
    for (int m = 32; m >= 1; m >>= 1) ss += __shfl_xor(ss, m);
    const float rn = rsqrtf(ss * (1.0f / 128.0f) + 1e-6f) * QK_SCALE;
    const float n0 = v0 * rn * (1.0f + qw[lane]);
    const float n1 = v1 * rn * (1.0f + qw[lane + 64]);
    const float c0 = cosT[(size_t)s * 128 + lane], c1 = cosT[(size_t)s * 128 + lane + 64];
    const float sn0 = sinT[(size_t)s * 128 + lane], sn1 = sinT[(size_t)s * 128 + lane + 64];
    u16* qb = Qb + ((size_t)(b * 16 + h) * S_LEN + s) * 128;
    qb[lane]      = f2bf(n0 * c0 - n1 * sn0);
    qb[lane + 64] = f2bf(n1 * c1 + n0 * sn1);
  } else if (bid < 20480) {               // knorm_rope
    const int idx = (bid - 16384) * 4 + wv;   // row*4 + g
    const int g = idx & 3, row = idx >> 2;
    const int s = row & (S_LEN - 1), b = row >> 11;
    const u16* base = QKV + (size_t)row * DQKV + DQG + g * 128;
    const float v0 = bf2f(base[lane]), v1 = bf2f(base[lane + 64]);
    float ss = v0 * v0 + v1 * v1;
#pragma unroll
    for (int m = 32; m >= 1; m >>= 1) ss += __shfl_xor(ss, m);
    const float rn = rsqrtf(ss * (1.0f / 128.0f) + 1e-6f);
    const float n0 = v0 * rn * (1.0f + kw[lane]);
    const float n1 = v1 * rn * (1.0f + kw[lane + 64]);
    const float c0 = cosT[(size_t)s * 128 + lane], c1 = cosT[(size_t)s * 128 + lane + 64];
    const float sn0 = sinT[(size_t)s * 128 + lane], sn1 = sinT[(size_t)s * 128 + lane + 64];
    u16* kb = Kb + ((size_t)(b * 4 + g) * S_LEN + s) * 128;
    const int sw = s & 7;
    const int d0 = lane, d1 = lane + 64;
    const int p0 = (((d0 >> 3) ^ sw) << 3) | (d0 & 7);
    const int p1 = (((d1 >> 3) ^ sw) << 3) | (d1 & 7);
    kb[p0] = f2bf(n0 * c0 - n1 * sn0);
    kb[p1] = f2bf(n1 * c1 + n0 * sn1);
  } else {                                // vtrans
    const int l = bid - 20480;            // bg*256 + d0chunk*64 + s0chunk
    const int bg = l >> 8, rem = l & 255;
    const int d0 = ((rem >> 6) & 3) * 32, s0 = (rem & 63) * 32;
    const int b = bg >> 2, g = bg & 3;
    const int t = threadIdx.x;
    {
      const int sl = t >> 3, dl4 = (t & 7) * 4;
      const ushort4 v = *reinterpret_cast<const ushort4*>(
          QKV + (size_t)(b * S_LEN + s0 + sl) * DQKV + DQG + 512 + g * 128 + d0 + dl4);
      tile[sl][dl4 + 0] = v.x; tile[sl][dl4 + 1] = v.y;
      tile[sl][dl4 + 2] = v.z; tile[sl][dl4 + 3] = v.w;
    }
    __syncthreads();
    {
      const int dl = t >> 3, sl4 = (t & 7) * 4;
      ushort4 o;
      o.x = tile[sl4 + 0][dl]; o.y = tile[sl4 + 1][dl];
      o.z = tile[sl4 + 2][dl]; o.w = tile[sl4 + 3][dl];
      const int d = d0 + dl, s = s0 + sl4;
      const size_t base = (size_t)(bg * 128 + d) * S_LEN + (s & ~63);
      const int pos = ((((s >> 3) & 7) ^ (d & 7)) << 3) | (s & 7);
      *reinterpret_cast<ushort4*>(Vt + base + pos) = o;
    }
  }
}

// ---------------- MFMA flash attention + gating (swapped QK^T, pipelined) ----------------
// (unchanged from round 7 — ~83 µs measured; held constant this round)
__global__ __launch_bounds__(256) void attn(const u16* __restrict__ Qb,
                                            const u16* __restrict__ Kb,
                                            const u16* __restrict__ Vt,
                                            const u16* __restrict__ QKV,
                                            u16* __restrict__ ctxg) {
  __shared__ __align__(16) u16 Ks[2][64 * 128];   // [slot][key][d], chunk-swizzled
  __shared__ __align__(16) u16 Vts[2][128 * 64];  // [slot][d][key], chunk-swizzled
  __shared__ __align__(16) u16 Ps[4][16 * 64];    // per-wave P [q=f][key], swizzled
  const int tid = threadIdx.x, wv = tid >> 6, lane = tid & 63;
  const int ip = blockIdx.x, bh = blockIdx.y;
  const int b = bh >> 4, h = bh & 15, g = h >> 2, bg = b * 4 + g;
  const int f = lane & 15, quad = lane >> 4, fq = quad * 8;
  const int fsw = f & 7;
  const u16* Kp = Kb + (size_t)bg * S_LEN * 128;
  const u16* Vp = Vt + (size_t)bg * 128 * S_LEN;
  u16* Pw = Ps[wv];
  const int pwr_base = f * 64 + ((quad & 1) << 2);
  const int pf0_off = f * 64 + ((quad ^ fsw) << 3);
  const int pf1_off = f * 64 + (((4 + quad) ^ fsw) << 3);

  auto stage_k = [&](int sl, int kt) {
    const int k0 = kt * 64;
#pragma unroll
    for (int i = 0; i < 4; ++i) {
      const int j = wv * 4 + i;
      gload_lds16(Kp + (size_t)k0 * 128 + j * 512 + lane * 8, &Ks[sl][j * 512]);
    }
  };
  auto stage_v = [&](int sl, int kt) {
    const int k0 = kt * 64;
#pragma unroll
    for (int i = 0; i < 4; ++i) {
      const int r0 = (wv * 4 + i) * 8;
      gload_lds16(Vp + (size_t)(r0 + (lane >> 3)) * S_LEN + k0 + (lane & 7) * 8,
                  &Vts[sl][r0 * 64]);
    }
  };

  for (int pass = 0; pass < 2; ++pass) {
    const int qt = pass ? 31 - ip : ip;
    const int qrow = qt * 64 + wv * 16 + f;
    const u16* Qp = Qb + ((size_t)bh * S_LEN + qt * 64 + wv * 16) * 128;
    bf16x8 aq[4];
#pragma unroll
    for (int c = 0; c < 4; ++c)
      aq[c] = *reinterpret_cast<const bf16x8*>(&Qp[(size_t)f * 128 + c * 32 + fq]);

    floatx4 o[8] = {};
    float lsum = 0.f;
    const int nkt = qt + 1;

    __syncthreads();
    stage_k(0, 0); stage_v(0, 0);
    if (nkt > 1) {
      stage_k(1, 1); stage_v(1, 1);
      asm volatile("s_waitcnt vmcnt(8)" ::: "memory");
    } else {
      asm volatile("s_waitcnt vmcnt(0)" ::: "memory");
    }
    __syncthreads();

    {
      floatx4 sc[4] = {};
#pragma unroll
      for (int c = 0; c < 4; ++c)
#pragma unroll
        for (int n = 0; n < 4; ++n) {
          bf16x8 bk = *reinterpret_cast<const bf16x8*>(
              &Ks[0][(n * 16 + f) * 128 + (((4 * c + quad) ^ fsw) << 3)]);
          sc[n] = __builtin_amdgcn_mfma_f32_16x16x32_bf16(bk, aq[c], sc[n], 0, 0, 0);
        }
#pragma unroll
      for (int n = 0; n < 4; ++n) {
        float pv_[4];
#pragma unroll
        for (int r = 0; r < 4; ++r) {
          const int key = n * 16 + quad * 4 + r;
          const float p = (key <= qrow) ? __expf(sc[n][r]) : 0.f;
          lsum += p; pv_[r] = p;
        }
        ushort4 pk;
        pk.x = f2bf(pv_[0]); pk.y = f2bf(pv_[1]); pk.z = f2bf(pv_[2]); pk.w = f2bf(pv_[3]);
        *reinterpret_cast<ushort4*>(
            &Pw[pwr_base + (((2 * n + (quad >> 1)) ^ fsw) << 3)]) = pk;
      }
    }
    if (nkt > 1) {
      asm volatile("s_waitcnt vmcnt(4)" ::: "memory");
      __syncthreads();
    }

    int cur = 0;
    for (int t = 0; t < nkt; ++t) {
      const bool more = (t + 1 < nkt);
      floatx4 sn[4] = {};
      if (more) {
#pragma unroll
        for (int c = 0; c < 4; ++c)
#pragma unroll
          for (int n = 0; n < 4; ++n) {
            bf16x8 bk = *reinterpret_cast<const bf16x8*>(
                &Ks[cur ^ 1][(n * 16 + f) * 128 + (((4 * c + quad) ^ fsw) << 3)]);
            sn[n] = __builtin_amdgcn_mfma_f32_16x16x32_bf16(bk, aq[c], sn[n], 0, 0, 0);
          }
        if (t + 2 < nkt) stage_k(cur, t + 2);
      }
      bf16x8 pf0 = *reinterpret_cast<const bf16x8*>(&Pw[pf0_off]);
      bf16x8 pf1 = *reinterpret_cast<const bf16x8*>(&Pw[pf1_off]);
#pragma unroll
      for (int dt = 0; dt < 8; ++dt) {
        bf16x8 bv = *reinterpret_cast<const bf16x8*>(
            &Vts[cur][(dt * 16 + f) * 64 + ((quad ^ fsw) << 3)]);
        o[dt] = __builtin_amdgcn_mfma_f32_16x16x32_bf16(pf0, bv, o[dt], 0, 0, 0);
      }
#pragma unroll
      for (int dt = 0; dt < 8; ++dt) {
        bf16x8 bv = *reinterpret_cast<const bf16x8*>(
            &Vts[cur][(dt * 16 + f) * 64 + (((4 + quad) ^ fsw) << 3)]);
        o[dt] = __builtin_amdgcn_mfma_f32_16x16x32_bf16(pf1, bv, o[dt], 0, 0, 0);
      }
      if (more) {
        const int kb = (t + 1) * 64;
#pragma unroll
        for (int n = 0; n < 4; ++n) {
          float pv_[4];
#pragma unroll
          for (int r = 0; r < 4; ++r) {
            const int key = kb + n * 16 + quad * 4 + r;
            const float p = (key <= qrow) ? __expf(sn[n][r]) : 0.f;
            lsum += p; pv_[r] = p;
          }
          ushort4 pk;
          pk.x = f2bf(pv_[0]); pk.y = f2bf(pv_[1]); pk.z = f2bf(pv_[2]); pk.w = f2bf(pv_[3]);
          *reinterpret_cast<ushort4*>(
              &Pw[pwr_base + (((2 * n + (quad >> 1)) ^ fsw) << 3)]) = pk;
        }
        __syncthreads();
        if (t + 2 < nkt) {
          stage_v(cur, t + 2);
          asm volatile("s_waitcnt vmcnt(4)" ::: "memory");
        } else {
          asm volatile("s_waitcnt vmcnt(0)" ::: "memory");
        }
        __syncthreads();
        cur ^= 1;
      }
    }

    lsum += __shfl_xor(lsum, 16);
    lsum += __shfl_xor(lsum, 32);
    const float inv = 1.0f / lsum;

#pragma unroll
    for (int r = 0; r < 4; ++r) {
      const float linv = __shfl(inv, quad * 4 + r);
      const int s = qt * 64 + wv * 16 + quad * 4 + r;
      const size_t grow = (size_t)b * S_LEN + s;
#pragma unroll
      for (int dt = 0; dt < 8; ++dt) {
        const int d = dt * 16 + f;
        const float gate = bf2f(QKV[grow * DQKV + h * 256 + 128 + d]);
        const float val = o[dt][r] * linv * (1.0f / (1.0f + __expf(-gate)));
        const int col = h * 128 + d;
        ctxg[grow * 2048 + swz(col, (int)grow)] = f2bf(val);
      }
    }
  }
}

extern "C" void kernel_launch(void* const* d_in, const int* in_sizes, int n_in,
                              void* d_out, int out_size, void* d_ws, size_t ws_size,
                              hipStream_t stream) {
  const float* x    = (const float*)d_in[0];
  const float* Wq   = (const float*)d_in[1];
  const float* Wk   = (const float*)d_in[2];
  const float* Wv   = (const float*)d_in[3];
  const float* Wo   = (const float*)d_in[4];
  const float* qnw  = (const float*)d_in[5];
  const float* knw  = (const float*)d_in[6];
  const float* cosT = (const float*)d_in[7];
  const float* sinT = (const float*)d_in[8];
  // d_in[9] = mask (unused; causality computed analytically)

  char* p = (char*)d_ws;
  u16*   xb    = (u16*)p;  p += (size_t)NROWS * DIN * 2;       // x bf16 (swizzled)
  u16*   WqkvT = (u16*)p;  p += (size_t)DQKV * DIN * 2;        // [Wq|Wk|Wv]^T (swizzled)
  u16*   WoT   = (u16*)p;  p += (size_t)2048 * 2048 * 2;       // Wo^T (swizzled)
  u16*   QKVb  = (u16*)p;  p += (size_t)NROWS * DQKV * 2;      // qkv proj bf16 (plain)
  u16*   Qbf   = (u16*)p;  p += (size_t)2 * 16 * S_LEN * 128 * 2;
  u16*   Kbf   = (u16*)p;  p += (size_t)2 * 4 * S_LEN * 128 * 2;
  u16*   Vtb   = (u16*)p;  p += (size_t)2 * 4 * S_LEN * 128 * 2;
  u16*   ctxg  = (u16*)p;  p += (size_t)NROWS * 2048 * 2;      // gated ctx (swizzled)

  // 1 launch: x-cvt + all 4 weight transposes
  prep<<<22528, 256, 0, stream>>>(x, Wq, Wk, Wv, Wo, xb, WqkvT, WoT);

  // Q|gate projection: 8-phase 256x256 pipeline, grid 16x16 = 256 WGs
  gemm256<<<dim3(16, 16), 512, 0, stream>>>(xb, WqkvT, QKVb, DIN, DQKV);
  // K|V projection: 128^2 tile, grid 8x32 = 256 WGs
  gemm_bt<true><<<dim3(8, 32), 256, 0, stream>>>(
      xb, WqkvT + (size_t)4096 * 2048, QKVb + 4096, NROWS, 1024, DIN, DQKV);

  // 1 launch: qnorm_rope + knorm_rope + vtrans
  postproj<<<22528, 256, 0, stream>>>(QKVb, qnw, knw, cosT, sinT, Qbf, Kbf, Vtb);

  attn<<<dim3(16, 32), 256, 0, stream>>>(Qbf, Kbf, Vtb, QKVb, ctxg);

  gemm_bt<false><<<dim3(16, 32), 256, 0, stream>>>(ctxg, WoT, (float*)d_out, NROWS, 2048, 2048, 2048);
}